// Round 3
// baseline (863.342 us; speedup 1.0000x reference)
//
#include <hip/hip_runtime.h>
#include <cstdint>

#define B_ 4096
#define N_ 64
#define K_ 48
#define D_ 64
#define F_ 4096
#define E_ 8
#define H_ 1024
#define O_ 512
#define T_ 2
#define TH_ 256
#define NSLOT (B_ * 2)

#define BM 128
#define BN 128
#define BK 64

typedef float f32x4 __attribute__((ext_vector_type(4)));
typedef __bf16 bf16x8 __attribute__((ext_vector_type(8)));

__device__ __forceinline__ unsigned short f2bf(float f) {
    union { float f; unsigned int u; } v; v.f = f;
    unsigned int u = v.u;
    u += 0x7FFFu + ((u >> 16) & 1u);   // RNE
    return (unsigned short)(u >> 16);
}

// async global->LDS, 16B per lane; LDS dest must be wave-uniform base (+lane*16 implicit)
__device__ __forceinline__ void gload_lds16(const void* gptr, void* lptr) {
    auto* g = reinterpret_cast<const __attribute__((address_space(1))) unsigned int*>(
        reinterpret_cast<uintptr_t>(gptr));
    auto* l = reinterpret_cast<__attribute__((address_space(3))) unsigned int*>(
        reinterpret_cast<uintptr_t>(lptr));
    __builtin_amdgcn_global_load_lds(g, l, 16, 0, 0);
}

// ---------------- 0. prefix sums of embW over k, bias folded in ----------------
__global__ __launch_bounds__(64) void prefix_kernel(
    const float* __restrict__ embW, const float* __restrict__ embB,
    float* __restrict__ P)
{
    int n = blockIdx.x;
    int lane = threadIdx.x;
    float acc = embB[n * D_ + lane];
    const float* wsrc = embW + (size_t)n * K_ * D_ + lane;
    float* dst = P + (size_t)n * K_ * D_ + lane;
    #pragma unroll 8
    for (int k = 0; k < K_; ++k) {
        dst[k * D_] = acc;
        acc += wsrc[k * D_];
    }
}

// ---------------- 1. PLE + embedding + gate logits ----------------
// one block per sample b; wave w handles features n = w*16..w*16+15; lane = d.
// uniform-bin PLE closed form: j = floor(K*x), emb = relu(P[n,j] + f*embW[n,j]).
__global__ __launch_bounds__(256) void ple_embed_kernel(
    const float* __restrict__ x, const float* __restrict__ plw,
    const float* __restrict__ plb, const float* __restrict__ embW,
    const float* __restrict__ P, const float* __restrict__ gateW,
    unsigned short* __restrict__ flat_bf, float* __restrict__ logits)
{
    __shared__ float gpart[4][E_];
    int b = blockIdx.x;
    int tid = threadIdx.x, lane = tid & 63, w = tid >> 6;

    float xl = x[b * N_ + lane];   // lane holds x for feature `lane`
    float gp[E_];
    #pragma unroll
    for (int e = 0; e < E_; ++e) gp[e] = 0.0f;

    #pragma unroll 4
    for (int i = 0; i < 16; ++i) {
        int n = w * 16 + i;
        float xn = __shfl(xl, n);                  // wave-uniform
        const float* pw = plw + n * K_;
        const float* pb = plb + n * K_;
        float t = fmaf(pw[0], xn, pb[0]);          // = K*x (pb[0]==0)
        int j = (int)t;
        j = max(0, min(K_ - 1, j));
        float f = fminf(fmaxf(fmaf(pw[j], xn, pb[j]), 0.0f), 1.0f);
        size_t base = ((size_t)n * K_ + j) * D_ + lane;
        float emb = fmaxf(fmaf(f, embW[base], P[base]), 0.0f);
        flat_bf[(size_t)b * F_ + n * D_ + lane] = f2bf(emb);

        const float4* gw4 = (const float4*)(gateW + (size_t)(n * D_ + lane) * E_);
        float4 g0 = gw4[0], g1 = gw4[1];
        gp[0] = fmaf(emb, g0.x, gp[0]);
        gp[1] = fmaf(emb, g0.y, gp[1]);
        gp[2] = fmaf(emb, g0.z, gp[2]);
        gp[3] = fmaf(emb, g0.w, gp[3]);
        gp[4] = fmaf(emb, g1.x, gp[4]);
        gp[5] = fmaf(emb, g1.y, gp[5]);
        gp[6] = fmaf(emb, g1.z, gp[6]);
        gp[7] = fmaf(emb, g1.w, gp[7]);
    }

    #pragma unroll
    for (int off = 32; off > 0; off >>= 1) {
        #pragma unroll
        for (int e = 0; e < E_; ++e) gp[e] += __shfl_down(gp[e], off);
    }
    if (lane == 0) {
        #pragma unroll
        for (int e = 0; e < E_; ++e) gpart[w][e] = gp[e];
    }
    __syncthreads();
    if (tid < E_)
        logits[b * E_ + tid] =
            gpart[0][tid] + gpart[1][tid] + gpart[2][tid] + gpart[3][tid];
}

// ---------------- 2. top-2 gating ----------------
__global__ __launch_bounds__(256) void gate_top2_kernel(
    const float* __restrict__ logits, const float* __restrict__ gate_b,
    int* __restrict__ topi, float* __restrict__ topg, int* __restrict__ counts)
{
    int b = blockIdx.x * 256 + threadIdx.x;
    int lane = threadIdx.x & 63;
    float l[E_];
    #pragma unroll
    for (int e = 0; e < E_; ++e) l[e] = logits[b * E_ + e] + gate_b[e];
    int e1 = 0; float v1 = l[0];
    #pragma unroll
    for (int e = 1; e < E_; ++e) if (l[e] > v1) { v1 = l[e]; e1 = e; }
    int e2 = -1; float v2 = -1e30f;
    #pragma unroll
    for (int e = 0; e < E_; ++e) if (e != e1 && l[e] > v2) { v2 = l[e]; e2 = e; }
    float ex = expf(v2 - v1);
    float g1 = 1.0f / (1.0f + ex);
    float g2 = ex / (1.0f + ex);
    topi[b * 2] = e1; topi[b * 2 + 1] = e2;
    topg[b * 2] = g1; topg[b * 2 + 1] = g2;
    #pragma unroll
    for (int e = 0; e < E_; ++e) {
        unsigned long long m1 = __ballot(e1 == e);
        unsigned long long m2 = __ballot(e2 == e);
        if (lane == 0) {
            int c = __popcll(m1) + __popcll(m2);
            if (c) atomicAdd(&counts[e], c);
        }
    }
}

// ---------------- 3. scan ----------------
__global__ void scan_kernel(const int* __restrict__ counts, int* __restrict__ offsets) {
    if (threadIdx.x == 0) {
        int s = 0;
        for (int e = 0; e < E_; ++e) { offsets[e] = s; s += counts[e]; }
        offsets[E_] = s;
    }
}

// ---------------- 4. scatter samples into per-expert slot lists ----------------
__global__ __launch_bounds__(256) void scatter_kernel(
    const int* __restrict__ topi, const float* __restrict__ topg,
    const int* __restrict__ offsets, int* __restrict__ cursors,
    int* __restrict__ rows, float* __restrict__ gatev)
{
    int b = blockIdx.x * 256 + threadIdx.x;
    int lane = threadIdx.x & 63;
    #pragma unroll
    for (int j = 0; j < 2; ++j) {
        int e = topi[b * 2 + j];
        float g = topg[b * 2 + j];
        #pragma unroll
        for (int ex = 0; ex < E_; ++ex) {
            unsigned long long m = __ballot(e == ex);
            if (e == ex) {
                int leader = __builtin_ctzll(m);
                int base = 0;
                if (lane == leader) base = atomicAdd(&cursors[ex], __popcll(m));
                base = __shfl(base, leader);
                int pos = base + __popcll(m & ((1ull << lane) - 1ull));
                int slot = offsets[ex] + pos;
                rows[slot] = b;
                gatev[slot] = g;
            }
        }
    }
}

// ---------------- 5. transpose+convert: (CH,R,C) f32 -> (CH,C,R) bf16 ----------------
// 64x64 tiles; full 64-lane coalescing on read (256B) and write (128B).
// LDS tile[64][65]: both access phases are <=2-way bank aliased (free).
__global__ __launch_bounds__(256) void transp_bf16_kernel(
    const float* __restrict__ in, unsigned short* __restrict__ out, int R, int C)
{
    __shared__ float tile[64][65];   // 16.6 KB
    int ch = blockIdx.z;
    const float* src = in + (size_t)ch * R * C;
    unsigned short* dst = out + (size_t)ch * R * C;
    int c0 = blockIdx.x * 64, r0 = blockIdx.y * 64;
    int lane = threadIdx.x & 63, w = threadIdx.x >> 6;
    #pragma unroll
    for (int i = 0; i < 16; ++i) {
        int r = w * 16 + i;
        tile[r][lane] = src[(size_t)(r0 + r) * C + c0 + lane];
    }
    __syncthreads();
    #pragma unroll
    for (int i = 0; i < 16; ++i) {
        int c = w * 16 + i;
        dst[(size_t)(c0 + c) * R + r0 + lane] = f2bf(tile[lane][c]);
    }
}

// ---------------- 6. FC1 split-K: partial sums -> fp32 atomic Hacc ----------------
// grid.z = E_*2: e = z>>1, split s = z&1 covers K range [s*F/2, (s+1)*F/2)
__global__ __launch_bounds__(256) void fc1_kernel(
    const unsigned short* __restrict__ Abf,   // flat_bf (B,F)
    const unsigned short* __restrict__ Wbt,   // (E,H,F) bf16
    const int* __restrict__ rows, const int* __restrict__ offsets,
    float* __restrict__ Hacc)                 // (NSLOT,H) f32, pre-zeroed
{
    int z = blockIdx.z;
    int e = z >> 1, s = z & 1;
    int m0 = offsets[e], mEnd = offsets[e + 1];
    int Me = mEnd - m0;
    int tr = blockIdx.x;
    if (tr * BM >= Me) return;
    int cn = blockIdx.y;

    __shared__ alignas(16) unsigned short As[BM * BK];
    __shared__ alignas(16) unsigned short Bs[BN * BK];

    int tid = threadIdx.x, lane = tid & 63, wv = tid >> 6;
    int lr = lane >> 3;       // 0..7 row within 8-row region
    int pchunk = lane & 7;    // LDS chunk position
    int cg = pchunk ^ lr;     // global 16B-chunk (XOR swizzle -> 2-way-only bank aliasing)

    const unsigned short* aptr[4];
    const unsigned short* bptr[4];
    #pragma unroll
    for (int i = 0; i < 4; ++i) {
        int reg = wv * 4 + i;
        int rowA = reg * 8 + lr;
        int slot = m0 + tr * BM + rowA;
        slot = min(slot, mEnd - 1);
        aptr[i] = Abf + (size_t)rows[slot] * F_ + cg * 8;
        int rowB = cn * BN + reg * 8 + lr;
        bptr[i] = Wbt + ((size_t)e * H_ + rowB) * (size_t)F_ + cg * 8;
    }

    f32x4 zero = {0.f, 0.f, 0.f, 0.f};
    f32x4 acc[4][4];
    #pragma unroll
    for (int i = 0; i < 4; ++i)
        #pragma unroll
        for (int j = 0; j < 4; ++j) acc[i][j] = zero;

    int wvM = wv >> 1, wvN = wv & 1;
    int m16 = lane & 15, q = lane >> 4;

    int kbeg = s * (F_ / 2), kend = kbeg + F_ / 2;
    for (int k0 = kbeg; k0 < kend; k0 += BK) {
        __syncthreads();
        #pragma unroll
        for (int i = 0; i < 4; ++i) {
            int reg = wv * 4 + i;
            gload_lds16(aptr[i] + k0, &As[reg * 512]);
            gload_lds16(bptr[i] + k0, &Bs[reg * 512]);
        }
        __syncthreads();
        #pragma unroll
        for (int ks = 0; ks < 2; ++ks) {
            bf16x8 af[4], bfg[4];
            #pragma unroll
            for (int mt = 0; mt < 4; ++mt) {
                int m = wvM * 64 + mt * 16 + m16;
                int pos = (ks * 4 + q) ^ (m & 7);
                af[mt] = *(const bf16x8*)&As[m * BK + pos * 8];
            }
            #pragma unroll
            for (int nt = 0; nt < 4; ++nt) {
                int n = wvN * 64 + nt * 16 + m16;
                int pos = (ks * 4 + q) ^ (n & 7);
                bfg[nt] = *(const bf16x8*)&Bs[n * BK + pos * 8];
            }
            #pragma unroll
            for (int mt = 0; mt < 4; ++mt)
                #pragma unroll
                for (int nt = 0; nt < 4; ++nt)
                    acc[mt][nt] = __builtin_amdgcn_mfma_f32_16x16x32_bf16(
                        af[mt], bfg[nt], acc[mt][nt], 0, 0, 0);
        }
    }

    #pragma unroll
    for (int nt = 0; nt < 4; ++nt) {
        int col = cn * BN + wvN * 64 + nt * 16 + m16;
        #pragma unroll
        for (int mt = 0; mt < 4; ++mt) {
            int rbase = tr * BM + wvM * 64 + mt * 16 + q * 4;
            #pragma unroll
            for (int r = 0; r < 4; ++r) {
                int rr = rbase + r;
                if (rr < Me)
                    atomicAdd(&Hacc[(size_t)(m0 + rr) * H_ + col], acc[mt][nt][r]);
            }
        }
    }
}

// ---------------- 6b. H epilogue: bias + relu + bf16 ----------------
__global__ __launch_bounds__(256) void h_epilogue_kernel(
    const float* __restrict__ Hacc, const float* __restrict__ bias,
    const int* __restrict__ offsets, unsigned short* __restrict__ Hbf)
{
    __shared__ int soff[E_];
    int slot = blockIdx.x;
    if (threadIdx.x < E_) soff[threadIdx.x] = offsets[threadIdx.x];
    __syncthreads();
    int e = 0;
    #pragma unroll
    for (int i = 1; i < E_; ++i) if (slot >= soff[i]) e = i;
    int c = threadIdx.x * 4;
    float4 v = *(const float4*)&Hacc[(size_t)slot * H_ + c];
    float4 bv = *(const float4*)&bias[e * H_ + c];
    unsigned int lo = f2bf(fmaxf(v.x + bv.x, 0.f)) |
                      ((unsigned int)f2bf(fmaxf(v.y + bv.y, 0.f)) << 16);
    unsigned int hi = f2bf(fmaxf(v.z + bv.z, 0.f)) |
                      ((unsigned int)f2bf(fmaxf(v.w + bv.w, 0.f)) << 16);
    uint2 pk = {lo, hi};
    *(uint2*)&Hbf[(size_t)slot * H_ + c] = pk;
}

// ---------------- 7. FC2 split-K: slot GEMM + gated atomic combine into moe ----------------
__global__ __launch_bounds__(256) void fc2_kernel(
    const unsigned short* __restrict__ Hbf,   // (NSLOT,H) bf16
    const unsigned short* __restrict__ Wbt,   // (E,O,H) bf16
    const float* __restrict__ bias,           // (E,O)
    const int* __restrict__ rows, const float* __restrict__ gatev,
    const int* __restrict__ offsets, float* __restrict__ moe)  // (B,O) f32
{
    int z = blockIdx.z;
    int e = z >> 1, s = z & 1;
    int m0 = offsets[e], mEnd = offsets[e + 1];
    int Me = mEnd - m0;
    int tr = blockIdx.x;
    if (tr * BM >= Me) return;
    int cn = blockIdx.y;

    __shared__ alignas(16) unsigned short As[BM * BK];
    __shared__ alignas(16) unsigned short Bs[BN * BK];

    int tid = threadIdx.x, lane = tid & 63, wv = tid >> 6;
    int lr = lane >> 3;
    int pchunk = lane & 7;
    int cg = pchunk ^ lr;

    const unsigned short* aptr[4];
    const unsigned short* bptr[4];
    #pragma unroll
    for (int i = 0; i < 4; ++i) {
        int reg = wv * 4 + i;
        int rowA = reg * 8 + lr;
        int slot = m0 + tr * BM + rowA;
        slot = min(slot, mEnd - 1);
        aptr[i] = Hbf + (size_t)slot * H_ + cg * 8;
        int rowB = cn * BN + reg * 8 + lr;
        bptr[i] = Wbt + ((size_t)e * O_ + rowB) * (size_t)H_ + cg * 8;
    }

    f32x4 zero = {0.f, 0.f, 0.f, 0.f};
    f32x4 acc[4][4];
    #pragma unroll
    for (int i = 0; i < 4; ++i)
        #pragma unroll
        for (int j = 0; j < 4; ++j) acc[i][j] = zero;

    int wvM = wv >> 1, wvN = wv & 1;
    int m16 = lane & 15, q = lane >> 4;

    int kbeg = s * (H_ / 2), kend = kbeg + H_ / 2;
    for (int k0 = kbeg; k0 < kend; k0 += BK) {
        __syncthreads();
        #pragma unroll
        for (int i = 0; i < 4; ++i) {
            int reg = wv * 4 + i;
            gload_lds16(aptr[i] + k0, &As[reg * 512]);
            gload_lds16(bptr[i] + k0, &Bs[reg * 512]);
        }
        __syncthreads();
        #pragma unroll
        for (int ks = 0; ks < 2; ++ks) {
            bf16x8 af[4], bfg[4];
            #pragma unroll
            for (int mt = 0; mt < 4; ++mt) {
                int m = wvM * 64 + mt * 16 + m16;
                int pos = (ks * 4 + q) ^ (m & 7);
                af[mt] = *(const bf16x8*)&As[m * BK + pos * 8];
            }
            #pragma unroll
            for (int nt = 0; nt < 4; ++nt) {
                int n = wvN * 64 + nt * 16 + m16;
                int pos = (ks * 4 + q) ^ (n & 7);
                bfg[nt] = *(const bf16x8*)&Bs[n * BK + pos * 8];
            }
            #pragma unroll
            for (int mt = 0; mt < 4; ++mt)
                #pragma unroll
                for (int nt = 0; nt < 4; ++nt)
                    acc[mt][nt] = __builtin_amdgcn_mfma_f32_16x16x32_bf16(
                        af[mt], bfg[nt], acc[mt][nt], 0, 0, 0);
        }
    }

    #pragma unroll
    for (int nt = 0; nt < 4; ++nt) {
        int col = cn * BN + wvN * 64 + nt * 16 + m16;
        float bv = (s == 0) ? bias[e * O_ + col] : 0.0f;
        #pragma unroll
        for (int mt = 0; mt < 4; ++mt) {
            int rbase = tr * BM + wvM * 64 + mt * 16 + q * 4;
            #pragma unroll
            for (int r = 0; r < 4; ++r) {
                int rr = rbase + r;
                if (rr < Me) {
                    int slot = m0 + rr;
                    float g = gatev[slot];
                    int b = rows[slot];
                    atomicAdd(&moe[(size_t)b * O_ + col], g * (acc[mt][nt][r] + bv));
                }
            }
        }
    }
}

// ---------------- 8. tower hidden: th = relu(moe @ tw1 + tb1), fp32 ----------------
__global__ __launch_bounds__(256) void tower1_kernel(
    const float* __restrict__ moe, const float* __restrict__ tw1,
    const float* __restrict__ tb1, float* __restrict__ th)
{
    __shared__ float ms[16 * O_];   // 32 KB
    int b0 = blockIdx.x * 16;
    int tid = threadIdx.x;
    for (int idx = tid; idx < 16 * O_; idx += 256)
        ms[idx] = moe[(size_t)b0 * O_ + idx];
    __syncthreads();

    int s = tid;   // 0..255 = TH index
    float acc0[16], acc1[16];
    float bv0 = tb1[s], bv1 = tb1[TH_ + s];
    #pragma unroll
    for (int i = 0; i < 16; ++i) { acc0[i] = bv0; acc1[i] = bv1; }

    for (int o = 0; o < O_; o += 4) {
        float w0[4], w1[4];
        #pragma unroll
        for (int u = 0; u < 4; ++u) {
            w0[u] = tw1[(size_t)(o + u) * TH_ + s];
            w1[u] = tw1[(size_t)(O_ + o + u) * TH_ + s];
        }
        #pragma unroll
        for (int smp = 0; smp < 16; ++smp) {
            float4 mv = *(const float4*)&ms[smp * O_ + o];
            acc0[smp] = fmaf(mv.x, w0[0], acc0[smp]);
            acc0[smp] = fmaf(mv.y, w0[1], acc0[smp]);
            acc0[smp] = fmaf(mv.z, w0[2], acc0[smp]);
            acc0[smp] = fmaf(mv.w, w0[3], acc0[smp]);
            acc1[smp] = fmaf(mv.x, w1[0], acc1[smp]);
            acc1[smp] = fmaf(mv.y, w1[1], acc1[smp]);
            acc1[smp] = fmaf(mv.z, w1[2], acc1[smp]);
            acc1[smp] = fmaf(mv.w, w1[3], acc1[smp]);
        }
    }
    #pragma unroll
    for (int smp = 0; smp < 16; ++smp) {
        int b = b0 + smp;
        th[((size_t)b * T_ + 0) * TH_ + s] = fmaxf(acc0[smp], 0.0f);
        th[((size_t)b * T_ + 1) * TH_ + s] = fmaxf(acc1[smp], 0.0f);
    }
}

// ---------------- 9. tower out: out[b][t] = th . tw2 + tb2 ----------------
__global__ __launch_bounds__(256) void tower2_kernel(
    const float* __restrict__ th, const float* __restrict__ tw2,
    const float* __restrict__ tb2, float* __restrict__ out)
{
    int tid = threadIdx.x, lane = tid & 63, w = tid >> 6;
    int pair = blockIdx.x * 4 + w;     // b*T + t
    int t = pair & 1;
    const float* tp = th + (size_t)pair * TH_;
    float p = 0.0f;
    #pragma unroll
    for (int j = 0; j < TH_ / 64; ++j) {
        int s = lane + j * 64;
        p = fmaf(tp[s], tw2[t * TH_ + s], p);
    }
    #pragma unroll
    for (int off = 32; off > 0; off >>= 1) p += __shfl_down(p, off);
    if (lane == 0) out[pair] = p + tb2[t];
}

extern "C" void kernel_launch(void* const* d_in, const int* in_sizes, int n_in,
                              void* d_out, int out_size, void* d_ws, size_t ws_size,
                              hipStream_t stream)
{
    const float* x     = (const float*)d_in[0];
    const float* plw   = (const float*)d_in[1];
    const float* plb   = (const float*)d_in[2];
    const float* embW  = (const float*)d_in[3];
    const float* embB  = (const float*)d_in[4];
    const float* gateW = (const float*)d_in[5];
    const float* gateB = (const float*)d_in[6];
    const float* eW1   = (const float*)d_in[7];
    const float* eB1   = (const float*)d_in[8];
    const float* eW2   = (const float*)d_in[9];
    const float* eB2   = (const float*)d_in[10];
    const float* tw1   = (const float*)d_in[11];
    const float* tb1   = (const float*)d_in[12];
    const float* tw2   = (const float*)d_in[13];
    const float* tb2   = (const float*)d_in[14];
    float* out = (float*)d_out;

    char* w = (char*)d_ws;
    auto alloc = [&](size_t bytes) {
        char* p = w; w += (bytes + 255) & ~(size_t)255; return p;
    };
    unsigned short* flat_bf = (unsigned short*)alloc((size_t)B_ * F_ * 2);      // 33.6 MB
    unsigned short* W1bt    = (unsigned short*)alloc((size_t)E_ * H_ * F_ * 2); // 67.1 MB
    unsigned short* W2bt    = (unsigned short*)alloc((size_t)E_ * O_ * H_ * 2); //  8.4 MB
    unsigned short* Hbf     = (unsigned short*)alloc((size_t)NSLOT * H_ * 2);   // 16.8 MB
    float* Hacc    = (float*)alloc((size_t)NSLOT * H_ * 4);                     // 33.6 MB
    float* Ppre    = (float*)alloc((size_t)N_ * K_ * D_ * 4);                   // 786 KB
    float* logits  = (float*)alloc((size_t)B_ * E_ * 4);
    float* moe     = (float*)alloc((size_t)B_ * O_ * 4);                        //  8.4 MB
    float* th      = (float*)alloc((size_t)B_ * T_ * TH_ * 4);                  //  8.4 MB
    int*   topi    = (int*)alloc((size_t)B_ * 2 * 4);
    float* topg    = (float*)alloc((size_t)B_ * 2 * 4);
    int*   rows    = (int*)alloc((size_t)NSLOT * 4);
    float* gatev   = (float*)alloc((size_t)NSLOT * 4);
    int*   counts  = (int*)alloc(E_ * 4);
    int*   offsets = (int*)alloc((E_ + 1) * 4);
    int*   cursors = (int*)alloc(E_ * 4);

    hipMemsetAsync(moe, 0, (size_t)B_ * O_ * 4, stream);
    hipMemsetAsync(Hacc, 0, (size_t)NSLOT * H_ * 4, stream);
    hipMemsetAsync(counts, 0, E_ * 4, stream);
    hipMemsetAsync(cursors, 0, E_ * 4, stream);

    prefix_kernel<<<N_, 64, 0, stream>>>(embW, embB, Ppre);
    ple_embed_kernel<<<B_, 256, 0, stream>>>(x, plw, plb, embW, Ppre, gateW,
                                             flat_bf, logits);
    transp_bf16_kernel<<<dim3(H_ / 64, F_ / 64, E_), 256, 0, stream>>>(eW1, W1bt, F_, H_);
    transp_bf16_kernel<<<dim3(O_ / 64, H_ / 64, E_), 256, 0, stream>>>(eW2, W2bt, H_, O_);
    gate_top2_kernel<<<B_ / 256, 256, 0, stream>>>(logits, gateB, topi, topg, counts);
    scan_kernel<<<1, 64, 0, stream>>>(counts, offsets);
    scatter_kernel<<<B_ / 256, 256, 0, stream>>>(topi, topg, offsets, cursors, rows, gatev);
    fc1_kernel<<<dim3(NSLOT / BM, H_ / BN, E_ * 2), 256, 0, stream>>>(flat_bf, W1bt,
                                                                      rows, offsets, Hacc);
    h_epilogue_kernel<<<NSLOT, 256, 0, stream>>>(Hacc, eB1, offsets, Hbf);
    fc2_kernel<<<dim3(NSLOT / BM, O_ / BN, E_ * 2), 256, 0, stream>>>(Hbf, W2bt, eB2,
                                                                      rows, gatev, offsets, moe);
    tower1_kernel<<<B_ / 16, 256, 0, stream>>>(moe, tw1, tb1, th);
    tower2_kernel<<<B_ * T_ / 4, 256, 0, stream>>>(th, tw2, tb2, out);
}

// Round 4
// 682.883 us; speedup vs baseline: 1.2643x; 1.2643x over previous
//
#include <hip/hip_runtime.h>
#include <cstdint>

#define B_ 4096
#define N_ 64
#define K_ 48
#define D_ 64
#define F_ 4096
#define E_ 8
#define H_ 1024
#define O_ 512
#define T_ 2
#define TH_ 256
#define NSLOT (B_ * 2)

#define BM 128
#define BN 128
#define BK 64

typedef float f32x4 __attribute__((ext_vector_type(4)));
typedef __bf16 bf16x8 __attribute__((ext_vector_type(8)));

__device__ __forceinline__ unsigned short f2bf(float f) {
    union { float f; unsigned int u; } v; v.f = f;
    unsigned int u = v.u;
    u += 0x7FFFu + ((u >> 16) & 1u);   // RNE
    return (unsigned short)(u >> 16);
}

// async global->LDS, 16B per lane; LDS dest must be wave-uniform base (+lane*16 implicit)
__device__ __forceinline__ void gload_lds16(const void* gptr, void* lptr) {
    auto* g = reinterpret_cast<const __attribute__((address_space(1))) unsigned int*>(
        reinterpret_cast<uintptr_t>(gptr));
    auto* l = reinterpret_cast<__attribute__((address_space(3))) unsigned int*>(
        reinterpret_cast<uintptr_t>(lptr));
    __builtin_amdgcn_global_load_lds(g, l, 16, 0, 0);
}

// ---------------- 0. prefix sums of embW over k, bias folded in ----------------
__global__ __launch_bounds__(64) void prefix_kernel(
    const float* __restrict__ embW, const float* __restrict__ embB,
    float* __restrict__ P)
{
    int n = blockIdx.x;
    int lane = threadIdx.x;
    float acc = embB[n * D_ + lane];
    const float* wsrc = embW + (size_t)n * K_ * D_ + lane;
    float* dst = P + (size_t)n * K_ * D_ + lane;
    #pragma unroll 8
    for (int k = 0; k < K_; ++k) {
        dst[k * D_] = acc;
        acc += wsrc[k * D_];
    }
}

// ---------------- 1. PLE + embedding + gate logits ----------------
__global__ __launch_bounds__(256) void ple_embed_kernel(
    const float* __restrict__ x, const float* __restrict__ plw,
    const float* __restrict__ plb, const float* __restrict__ embW,
    const float* __restrict__ P, const float* __restrict__ gateW,
    unsigned short* __restrict__ flat_bf, float* __restrict__ logits)
{
    __shared__ float gpart[4][E_];
    int b = blockIdx.x;
    int tid = threadIdx.x, lane = tid & 63, w = tid >> 6;

    float xl = x[b * N_ + lane];   // lane holds x for feature `lane`
    float gp[E_];
    #pragma unroll
    for (int e = 0; e < E_; ++e) gp[e] = 0.0f;

    #pragma unroll 4
    for (int i = 0; i < 16; ++i) {
        int n = w * 16 + i;
        float xn = __shfl(xl, n);                  // wave-uniform
        const float* pw = plw + n * K_;
        const float* pb = plb + n * K_;
        float t = fmaf(pw[0], xn, pb[0]);          // = K*x (pb[0]==0)
        int j = (int)t;
        j = max(0, min(K_ - 1, j));
        float f = fminf(fmaxf(fmaf(pw[j], xn, pb[j]), 0.0f), 1.0f);
        size_t base = ((size_t)n * K_ + j) * D_ + lane;
        float emb = fmaxf(fmaf(f, embW[base], P[base]), 0.0f);
        flat_bf[(size_t)b * F_ + n * D_ + lane] = f2bf(emb);

        const float4* gw4 = (const float4*)(gateW + (size_t)(n * D_ + lane) * E_);
        float4 g0 = gw4[0], g1 = gw4[1];
        gp[0] = fmaf(emb, g0.x, gp[0]);
        gp[1] = fmaf(emb, g0.y, gp[1]);
        gp[2] = fmaf(emb, g0.z, gp[2]);
        gp[3] = fmaf(emb, g0.w, gp[3]);
        gp[4] = fmaf(emb, g1.x, gp[4]);
        gp[5] = fmaf(emb, g1.y, gp[5]);
        gp[6] = fmaf(emb, g1.z, gp[6]);
        gp[7] = fmaf(emb, g1.w, gp[7]);
    }

    #pragma unroll
    for (int off = 32; off > 0; off >>= 1) {
        #pragma unroll
        for (int e = 0; e < E_; ++e) gp[e] += __shfl_down(gp[e], off);
    }
    if (lane == 0) {
        #pragma unroll
        for (int e = 0; e < E_; ++e) gpart[w][e] = gp[e];
    }
    __syncthreads();
    if (tid < E_)
        logits[b * E_ + tid] =
            gpart[0][tid] + gpart[1][tid] + gpart[2][tid] + gpart[3][tid];
}

// ---------------- 2. top-2 gating ----------------
__global__ __launch_bounds__(256) void gate_top2_kernel(
    const float* __restrict__ logits, const float* __restrict__ gate_b,
    int* __restrict__ topi, float* __restrict__ topg, int* __restrict__ counts)
{
    int b = blockIdx.x * 256 + threadIdx.x;
    int lane = threadIdx.x & 63;
    float l[E_];
    #pragma unroll
    for (int e = 0; e < E_; ++e) l[e] = logits[b * E_ + e] + gate_b[e];
    int e1 = 0; float v1 = l[0];
    #pragma unroll
    for (int e = 1; e < E_; ++e) if (l[e] > v1) { v1 = l[e]; e1 = e; }
    int e2 = -1; float v2 = -1e30f;
    #pragma unroll
    for (int e = 0; e < E_; ++e) if (e != e1 && l[e] > v2) { v2 = l[e]; e2 = e; }
    float ex = expf(v2 - v1);
    float g1 = 1.0f / (1.0f + ex);
    float g2 = ex / (1.0f + ex);
    topi[b * 2] = e1; topi[b * 2 + 1] = e2;
    topg[b * 2] = g1; topg[b * 2 + 1] = g2;
    #pragma unroll
    for (int e = 0; e < E_; ++e) {
        unsigned long long m1 = __ballot(e1 == e);
        unsigned long long m2 = __ballot(e2 == e);
        if (lane == 0) {
            int c = __popcll(m1) + __popcll(m2);
            if (c) atomicAdd(&counts[e], c);
        }
    }
}

// ---------------- 3. scan ----------------
__global__ void scan_kernel(const int* __restrict__ counts, int* __restrict__ offsets) {
    if (threadIdx.x == 0) {
        int s = 0;
        for (int e = 0; e < E_; ++e) { offsets[e] = s; s += counts[e]; }
        offsets[E_] = s;
    }
}

// ---------------- 4. scatter samples into per-expert slot lists ----------------
__global__ __launch_bounds__(256) void scatter_kernel(
    const int* __restrict__ topi, const float* __restrict__ topg,
    const int* __restrict__ offsets, int* __restrict__ cursors,
    int* __restrict__ rows, float* __restrict__ gatev)
{
    int b = blockIdx.x * 256 + threadIdx.x;
    int lane = threadIdx.x & 63;
    #pragma unroll
    for (int j = 0; j < 2; ++j) {
        int e = topi[b * 2 + j];
        float g = topg[b * 2 + j];
        #pragma unroll
        for (int ex = 0; ex < E_; ++ex) {
            unsigned long long m = __ballot(e == ex);
            if (e == ex) {
                int leader = __builtin_ctzll(m);
                int base = 0;
                if (lane == leader) base = atomicAdd(&cursors[ex], __popcll(m));
                base = __shfl(base, leader);
                int pos = base + __popcll(m & ((1ull << lane) - 1ull));
                int slot = offsets[ex] + pos;
                rows[slot] = b;
                gatev[slot] = g;
            }
        }
    }
}

// ---------------- 5. transpose+convert: (CH,R,C) f32 -> (CH,C,R) bf16 ----------------
__global__ __launch_bounds__(256) void transp_bf16_kernel(
    const float* __restrict__ in, unsigned short* __restrict__ out, int R, int C)
{
    __shared__ float tile[64][65];   // 16.6 KB
    int ch = blockIdx.z;
    const float* src = in + (size_t)ch * R * C;
    unsigned short* dst = out + (size_t)ch * R * C;
    int c0 = blockIdx.x * 64, r0 = blockIdx.y * 64;
    int lane = threadIdx.x & 63, w = threadIdx.x >> 6;
    #pragma unroll
    for (int i = 0; i < 16; ++i) {
        int r = w * 16 + i;
        tile[r][lane] = src[(size_t)(r0 + r) * C + c0 + lane];
    }
    __syncthreads();
    #pragma unroll
    for (int i = 0; i < 16; ++i) {
        int c = w * 16 + i;
        dst[(size_t)(c0 + c) * R + r0 + lane] = f2bf(tile[lane][c]);
    }
}

// ---------------- 6. FC1 split-K: partial sums -> Hacc[s] planes (no atomics) --------
// grid = (cn = H/BN, z = E*2, tr = NSLOT/BM): tr slowest so active blocks form a
// contiguous linear prefix -> uniform CU/XCD spread (round-3 fix: tr-fastest
// aliased all active blocks onto ~1/8 of the CUs).
__global__ __launch_bounds__(256) void fc1_kernel(
    const unsigned short* __restrict__ Abf,   // flat_bf (B,F)
    const unsigned short* __restrict__ Wbt,   // (E,H,F) bf16
    const int* __restrict__ rows, const int* __restrict__ offsets,
    float* __restrict__ Hacc)                 // (2,NSLOT,H) f32 planes
{
    int z = blockIdx.y;
    int e = z >> 1, s = z & 1;
    int m0 = offsets[e], mEnd = offsets[e + 1];
    int Me = mEnd - m0;
    int tr = blockIdx.z;
    if (tr * BM >= Me) return;
    int cn = blockIdx.x;

    __shared__ alignas(16) unsigned short As[BM * BK];
    __shared__ alignas(16) unsigned short Bs[BN * BK];

    int tid = threadIdx.x, lane = tid & 63, wv = tid >> 6;
    int lr = lane >> 3;       // 0..7 row within 8-row region
    int pchunk = lane & 7;    // LDS chunk position
    int cg = pchunk ^ lr;     // global 16B-chunk (XOR swizzle -> 2-way-only bank aliasing)

    const unsigned short* aptr[4];
    const unsigned short* bptr[4];
    #pragma unroll
    for (int i = 0; i < 4; ++i) {
        int reg = wv * 4 + i;
        int rowA = reg * 8 + lr;
        int slot = m0 + tr * BM + rowA;
        slot = min(slot, mEnd - 1);
        aptr[i] = Abf + (size_t)rows[slot] * F_ + cg * 8;
        int rowB = cn * BN + reg * 8 + lr;
        bptr[i] = Wbt + ((size_t)e * H_ + rowB) * (size_t)F_ + cg * 8;
    }

    f32x4 zero = {0.f, 0.f, 0.f, 0.f};
    f32x4 acc[4][4];
    #pragma unroll
    for (int i = 0; i < 4; ++i)
        #pragma unroll
        for (int j = 0; j < 4; ++j) acc[i][j] = zero;

    int wvM = wv >> 1, wvN = wv & 1;
    int m16 = lane & 15, q = lane >> 4;

    int kbeg = s * (F_ / 2), kend = kbeg + F_ / 2;
    for (int k0 = kbeg; k0 < kend; k0 += BK) {
        __syncthreads();
        #pragma unroll
        for (int i = 0; i < 4; ++i) {
            int reg = wv * 4 + i;
            gload_lds16(aptr[i] + k0, &As[reg * 512]);
            gload_lds16(bptr[i] + k0, &Bs[reg * 512]);
        }
        __syncthreads();
        #pragma unroll
        for (int ks = 0; ks < 2; ++ks) {
            bf16x8 af[4], bfg[4];
            #pragma unroll
            for (int mt = 0; mt < 4; ++mt) {
                int m = wvM * 64 + mt * 16 + m16;
                int pos = (ks * 4 + q) ^ (m & 7);
                af[mt] = *(const bf16x8*)&As[m * BK + pos * 8];
            }
            #pragma unroll
            for (int nt = 0; nt < 4; ++nt) {
                int n = wvN * 64 + nt * 16 + m16;
                int pos = (ks * 4 + q) ^ (n & 7);
                bfg[nt] = *(const bf16x8*)&Bs[n * BK + pos * 8];
            }
            #pragma unroll
            for (int mt = 0; mt < 4; ++mt)
                #pragma unroll
                for (int nt = 0; nt < 4; ++nt)
                    acc[mt][nt] = __builtin_amdgcn_mfma_f32_16x16x32_bf16(
                        af[mt], bfg[nt], acc[mt][nt], 0, 0, 0);
        }
    }

    float* hp = Hacc + (size_t)s * NSLOT * H_;
    #pragma unroll
    for (int nt = 0; nt < 4; ++nt) {
        int col = cn * BN + wvN * 64 + nt * 16 + m16;
        #pragma unroll
        for (int mt = 0; mt < 4; ++mt) {
            int rbase = tr * BM + wvM * 64 + mt * 16 + q * 4;
            #pragma unroll
            for (int r = 0; r < 4; ++r) {
                int rr = rbase + r;
                if (rr < Me)
                    hp[(size_t)(m0 + rr) * H_ + col] = acc[mt][nt][r];
            }
        }
    }
}

// ---------------- 6b. H epilogue: sum split planes + bias + relu + bf16 ----------------
__global__ __launch_bounds__(256) void h_epilogue_kernel(
    const float* __restrict__ Hacc, const float* __restrict__ bias,
    const int* __restrict__ offsets, unsigned short* __restrict__ Hbf)
{
    __shared__ int soff[E_];
    int slot = blockIdx.x;
    if (threadIdx.x < E_) soff[threadIdx.x] = offsets[threadIdx.x];
    __syncthreads();
    int e = 0;
    #pragma unroll
    for (int i = 1; i < E_; ++i) if (slot >= soff[i]) e = i;
    int c = threadIdx.x * 4;
    float4 v0 = *(const float4*)&Hacc[(size_t)slot * H_ + c];
    float4 v1 = *(const float4*)&Hacc[((size_t)NSLOT + slot) * H_ + c];
    float4 bv = *(const float4*)&bias[e * H_ + c];
    unsigned int lo = f2bf(fmaxf(v0.x + v1.x + bv.x, 0.f)) |
                      ((unsigned int)f2bf(fmaxf(v0.y + v1.y + bv.y, 0.f)) << 16);
    unsigned int hi = f2bf(fmaxf(v0.z + v1.z + bv.z, 0.f)) |
                      ((unsigned int)f2bf(fmaxf(v0.w + v1.w + bv.w, 0.f)) << 16);
    uint2 pk = {lo, hi};
    *(uint2*)&Hbf[(size_t)slot * H_ + c] = pk;
}

// ---------------- 7. FC2 split-K: slot GEMM + gated atomic combine into moe ----------------
// grid = (cn, z, tr), tr slowest (see fc1 comment).
__global__ __launch_bounds__(256) void fc2_kernel(
    const unsigned short* __restrict__ Hbf,   // (NSLOT,H) bf16
    const unsigned short* __restrict__ Wbt,   // (E,O,H) bf16
    const float* __restrict__ bias,           // (E,O)
    const int* __restrict__ rows, const float* __restrict__ gatev,
    const int* __restrict__ offsets, float* __restrict__ moe)  // (B,O) f32
{
    int z = blockIdx.y;
    int e = z >> 1, s = z & 1;
    int m0 = offsets[e], mEnd = offsets[e + 1];
    int Me = mEnd - m0;
    int tr = blockIdx.z;
    if (tr * BM >= Me) return;
    int cn = blockIdx.x;

    __shared__ alignas(16) unsigned short As[BM * BK];
    __shared__ alignas(16) unsigned short Bs[BN * BK];

    int tid = threadIdx.x, lane = tid & 63, wv = tid >> 6;
    int lr = lane >> 3;
    int pchunk = lane & 7;
    int cg = pchunk ^ lr;

    const unsigned short* aptr[4];
    const unsigned short* bptr[4];
    #pragma unroll
    for (int i = 0; i < 4; ++i) {
        int reg = wv * 4 + i;
        int rowA = reg * 8 + lr;
        int slot = m0 + tr * BM + rowA;
        slot = min(slot, mEnd - 1);
        aptr[i] = Hbf + (size_t)slot * H_ + cg * 8;
        int rowB = cn * BN + reg * 8 + lr;
        bptr[i] = Wbt + ((size_t)e * O_ + rowB) * (size_t)H_ + cg * 8;
    }

    f32x4 zero = {0.f, 0.f, 0.f, 0.f};
    f32x4 acc[4][4];
    #pragma unroll
    for (int i = 0; i < 4; ++i)
        #pragma unroll
        for (int j = 0; j < 4; ++j) acc[i][j] = zero;

    int wvM = wv >> 1, wvN = wv & 1;
    int m16 = lane & 15, q = lane >> 4;

    int kbeg = s * (H_ / 2), kend = kbeg + H_ / 2;
    for (int k0 = kbeg; k0 < kend; k0 += BK) {
        __syncthreads();
        #pragma unroll
        for (int i = 0; i < 4; ++i) {
            int reg = wv * 4 + i;
            gload_lds16(aptr[i] + k0, &As[reg * 512]);
            gload_lds16(bptr[i] + k0, &Bs[reg * 512]);
        }
        __syncthreads();
        #pragma unroll
        for (int ks = 0; ks < 2; ++ks) {
            bf16x8 af[4], bfg[4];
            #pragma unroll
            for (int mt = 0; mt < 4; ++mt) {
                int m = wvM * 64 + mt * 16 + m16;
                int pos = (ks * 4 + q) ^ (m & 7);
                af[mt] = *(const bf16x8*)&As[m * BK + pos * 8];
            }
            #pragma unroll
            for (int nt = 0; nt < 4; ++nt) {
                int n = wvN * 64 + nt * 16 + m16;
                int pos = (ks * 4 + q) ^ (n & 7);
                bfg[nt] = *(const bf16x8*)&Bs[n * BK + pos * 8];
            }
            #pragma unroll
            for (int mt = 0; mt < 4; ++mt)
                #pragma unroll
                for (int nt = 0; nt < 4; ++nt)
                    acc[mt][nt] = __builtin_amdgcn_mfma_f32_16x16x32_bf16(
                        af[mt], bfg[nt], acc[mt][nt], 0, 0, 0);
        }
    }

    #pragma unroll
    for (int nt = 0; nt < 4; ++nt) {
        int col = cn * BN + wvN * 64 + nt * 16 + m16;
        float bv = (s == 0) ? bias[e * O_ + col] : 0.0f;
        #pragma unroll
        for (int mt = 0; mt < 4; ++mt) {
            int rbase = tr * BM + wvM * 64 + mt * 16 + q * 4;
            #pragma unroll
            for (int r = 0; r < 4; ++r) {
                int rr = rbase + r;
                if (rr < Me) {
                    int slot = m0 + rr;
                    float g = gatev[slot];
                    int b = rows[slot];
                    atomicAdd(&moe[(size_t)b * O_ + col], g * (acc[mt][nt][r] + bv));
                }
            }
        }
    }
}

// ---------------- 8. tower hidden: th = relu(moe @ tw1 + tb1), fp32 ----------------
__global__ __launch_bounds__(256) void tower1_kernel(
    const float* __restrict__ moe, const float* __restrict__ tw1,
    const float* __restrict__ tb1, float* __restrict__ th)
{
    __shared__ float ms[16 * O_];   // 32 KB
    int b0 = blockIdx.x * 16;
    int tid = threadIdx.x;
    for (int idx = tid; idx < 16 * O_; idx += 256)
        ms[idx] = moe[(size_t)b0 * O_ + idx];
    __syncthreads();

    int s = tid;   // 0..255 = TH index
    float acc0[16], acc1[16];
    float bv0 = tb1[s], bv1 = tb1[TH_ + s];
    #pragma unroll
    for (int i = 0; i < 16; ++i) { acc0[i] = bv0; acc1[i] = bv1; }

    for (int o = 0; o < O_; o += 4) {
        float w0[4], w1[4];
        #pragma unroll
        for (int u = 0; u < 4; ++u) {
            w0[u] = tw1[(size_t)(o + u) * TH_ + s];
            w1[u] = tw1[(size_t)(O_ + o + u) * TH_ + s];
        }
        #pragma unroll
        for (int smp = 0; smp < 16; ++smp) {
            float4 mv = *(const float4*)&ms[smp * O_ + o];
            acc0[smp] = fmaf(mv.x, w0[0], acc0[smp]);
            acc0[smp] = fmaf(mv.y, w0[1], acc0[smp]);
            acc0[smp] = fmaf(mv.z, w0[2], acc0[smp]);
            acc0[smp] = fmaf(mv.w, w0[3], acc0[smp]);
            acc1[smp] = fmaf(mv.x, w1[0], acc1[smp]);
            acc1[smp] = fmaf(mv.y, w1[1], acc1[smp]);
            acc1[smp] = fmaf(mv.z, w1[2], acc1[smp]);
            acc1[smp] = fmaf(mv.w, w1[3], acc1[smp]);
        }
    }
    #pragma unroll
    for (int smp = 0; smp < 16; ++smp) {
        int b = b0 + smp;
        th[((size_t)b * T_ + 0) * TH_ + s] = fmaxf(acc0[smp], 0.0f);
        th[((size_t)b * T_ + 1) * TH_ + s] = fmaxf(acc1[smp], 0.0f);
    }
}

// ---------------- 9. tower out: out[b][t] = th . tw2 + tb2 ----------------
__global__ __launch_bounds__(256) void tower2_kernel(
    const float* __restrict__ th, const float* __restrict__ tw2,
    const float* __restrict__ tb2, float* __restrict__ out)
{
    int tid = threadIdx.x, lane = tid & 63, w = tid >> 6;
    int pair = blockIdx.x * 4 + w;     // b*T + t
    int t = pair & 1;
    const float* tp = th + (size_t)pair * TH_;
    float p = 0.0f;
    #pragma unroll
    for (int j = 0; j < TH_ / 64; ++j) {
        int s = lane + j * 64;
        p = fmaf(tp[s], tw2[t * TH_ + s], p);
    }
    #pragma unroll
    for (int off = 32; off > 0; off >>= 1) p += __shfl_down(p, off);
    if (lane == 0) out[pair] = p + tb2[t];
}

extern "C" void kernel_launch(void* const* d_in, const int* in_sizes, int n_in,
                              void* d_out, int out_size, void* d_ws, size_t ws_size,
                              hipStream_t stream)
{
    const float* x     = (const float*)d_in[0];
    const float* plw   = (const float*)d_in[1];
    const float* plb   = (const float*)d_in[2];
    const float* embW  = (const float*)d_in[3];
    const float* embB  = (const float*)d_in[4];
    const float* gateW = (const float*)d_in[5];
    const float* gateB = (const float*)d_in[6];
    const float* eW1   = (const float*)d_in[7];
    const float* eB1   = (const float*)d_in[8];
    const float* eW2   = (const float*)d_in[9];
    const float* eB2   = (const float*)d_in[10];
    const float* tw1   = (const float*)d_in[11];
    const float* tb1   = (const float*)d_in[12];
    const float* tw2   = (const float*)d_in[13];
    const float* tb2   = (const float*)d_in[14];
    float* out = (float*)d_out;

    char* w = (char*)d_ws;
    auto alloc = [&](size_t bytes) {
        char* p = w; w += (bytes + 255) & ~(size_t)255; return p;
    };
    unsigned short* flat_bf = (unsigned short*)alloc((size_t)B_ * F_ * 2);      // 33.6 MB
    unsigned short* W1bt    = (unsigned short*)alloc((size_t)E_ * H_ * F_ * 2); // 67.1 MB
    unsigned short* W2bt    = (unsigned short*)alloc((size_t)E_ * O_ * H_ * 2); //  8.4 MB
    unsigned short* Hbf     = (unsigned short*)alloc((size_t)NSLOT * H_ * 2);   // 16.8 MB
    float* Hacc    = (float*)alloc((size_t)2 * NSLOT * H_ * 4);                 // 67.1 MB
    float* Ppre    = (float*)alloc((size_t)N_ * K_ * D_ * 4);                   // 786 KB
    float* logits  = (float*)alloc((size_t)B_ * E_ * 4);
    float* moe     = (float*)alloc((size_t)B_ * O_ * 4);                        //  8.4 MB
    float* th      = (float*)alloc((size_t)B_ * T_ * TH_ * 4);                  //  8.4 MB
    int*   topi    = (int*)alloc((size_t)B_ * 2 * 4);
    float* topg    = (float*)alloc((size_t)B_ * 2 * 4);
    int*   rows    = (int*)alloc((size_t)NSLOT * 4);
    float* gatev   = (float*)alloc((size_t)NSLOT * 4);
    int*   counts  = (int*)alloc(E_ * 4);
    int*   offsets = (int*)alloc((E_ + 1) * 4);
    int*   cursors = (int*)alloc(E_ * 4);

    hipMemsetAsync(moe, 0, (size_t)B_ * O_ * 4, stream);
    hipMemsetAsync(counts, 0, E_ * 4, stream);
    hipMemsetAsync(cursors, 0, E_ * 4, stream);

    prefix_kernel<<<N_, 64, 0, stream>>>(embW, embB, Ppre);
    ple_embed_kernel<<<B_, 256, 0, stream>>>(x, plw, plb, embW, Ppre, gateW,
                                             flat_bf, logits);
    transp_bf16_kernel<<<dim3(H_ / 64, F_ / 64, E_), 256, 0, stream>>>(eW1, W1bt, F_, H_);
    transp_bf16_kernel<<<dim3(O_ / 64, H_ / 64, E_), 256, 0, stream>>>(eW2, W2bt, H_, O_);
    gate_top2_kernel<<<B_ / 256, 256, 0, stream>>>(logits, gateB, topi, topg, counts);
    scan_kernel<<<1, 64, 0, stream>>>(counts, offsets);
    scatter_kernel<<<B_ / 256, 256, 0, stream>>>(topi, topg, offsets, cursors, rows, gatev);
    fc1_kernel<<<dim3(H_ / BN, E_ * 2, NSLOT / BM), 256, 0, stream>>>(flat_bf, W1bt,
                                                                      rows, offsets, Hacc);
    h_epilogue_kernel<<<NSLOT, 256, 0, stream>>>(Hacc, eB1, offsets, Hbf);
    fc2_kernel<<<dim3(O_ / BN, E_ * 2, NSLOT / BM), 256, 0, stream>>>(Hbf, W2bt, eB2,
                                                                      rows, gatev, offsets, moe);
    tower1_kernel<<<B_ / 16, 256, 0, stream>>>(moe, tw1, tb1, th);
    tower2_kernel<<<B_ * T_ / 4, 256, 0, stream>>>(th, tw2, tb2, out);
}

// Round 5
// 601.058 us; speedup vs baseline: 1.4364x; 1.1361x over previous
//
#include <hip/hip_runtime.h>
#include <cstdint>

#define B_ 4096
#define N_ 64
#define K_ 48
#define D_ 64
#define F_ 4096
#define E_ 8
#define H_ 1024
#define O_ 512
#define T_ 2
#define TH_ 256
#define NSLOT (B_ * 2)

// fc1 tile: 128x64, fc2 tile: 64x64, both BK=64
#define MAXT1 72    // sum ceil(Me/128) <= 64+7
#define MAXT2 136   // sum ceil(Me/64)  <= 128+7

typedef float f32x4 __attribute__((ext_vector_type(4)));
typedef __bf16 bf16x8 __attribute__((ext_vector_type(8)));

__device__ __forceinline__ unsigned short f2bf(float f) {
    union { float f; unsigned int u; } v; v.f = f;
    unsigned int u = v.u;
    u += 0x7FFFu + ((u >> 16) & 1u);   // RNE
    return (unsigned short)(u >> 16);
}

__device__ __forceinline__ void gload_lds16(const void* gptr, void* lptr) {
    auto* g = reinterpret_cast<const __attribute__((address_space(1))) unsigned int*>(
        reinterpret_cast<uintptr_t>(gptr));
    auto* l = reinterpret_cast<__attribute__((address_space(3))) unsigned int*>(
        reinterpret_cast<uintptr_t>(lptr));
    __builtin_amdgcn_global_load_lds(g, l, 16, 0, 0);
}

// ---------------- 0. prefix sums of embW over k, bias folded in ----------------
__global__ __launch_bounds__(64) void prefix_kernel(
    const float* __restrict__ embW, const float* __restrict__ embB,
    float* __restrict__ P)
{
    int n = blockIdx.x;
    int lane = threadIdx.x;
    float acc = embB[n * D_ + lane];
    const float* wsrc = embW + (size_t)n * K_ * D_ + lane;
    float* dst = P + (size_t)n * K_ * D_ + lane;
    #pragma unroll 8
    for (int k = 0; k < K_; ++k) {
        dst[k * D_] = acc;
        acc += wsrc[k * D_];
    }
}

// ---------------- 1. PLE + embedding + gate logits ----------------
__global__ __launch_bounds__(256) void ple_embed_kernel(
    const float* __restrict__ x, const float* __restrict__ plw,
    const float* __restrict__ plb, const float* __restrict__ embW,
    const float* __restrict__ P, const float* __restrict__ gateW,
    unsigned short* __restrict__ flat_bf, float* __restrict__ logits)
{
    __shared__ float gpart[4][E_];
    int b = blockIdx.x;
    int tid = threadIdx.x, lane = tid & 63, w = tid >> 6;

    float xl = x[b * N_ + lane];
    float gp[E_];
    #pragma unroll
    for (int e = 0; e < E_; ++e) gp[e] = 0.0f;

    #pragma unroll 4
    for (int i = 0; i < 16; ++i) {
        int n = w * 16 + i;
        float xn = __shfl(xl, n);
        const float* pw = plw + n * K_;
        const float* pb = plb + n * K_;
        float t = fmaf(pw[0], xn, pb[0]);          // = K*x
        int j = (int)t;
        j = max(0, min(K_ - 1, j));
        float f = fminf(fmaxf(fmaf(pw[j], xn, pb[j]), 0.0f), 1.0f);
        size_t base = ((size_t)n * K_ + j) * D_ + lane;
        float emb = fmaxf(fmaf(f, embW[base], P[base]), 0.0f);
        flat_bf[(size_t)b * F_ + n * D_ + lane] = f2bf(emb);

        const float4* gw4 = (const float4*)(gateW + (size_t)(n * D_ + lane) * E_);
        float4 g0 = gw4[0], g1 = gw4[1];
        gp[0] = fmaf(emb, g0.x, gp[0]);
        gp[1] = fmaf(emb, g0.y, gp[1]);
        gp[2] = fmaf(emb, g0.z, gp[2]);
        gp[3] = fmaf(emb, g0.w, gp[3]);
        gp[4] = fmaf(emb, g1.x, gp[4]);
        gp[5] = fmaf(emb, g1.y, gp[5]);
        gp[6] = fmaf(emb, g1.z, gp[6]);
        gp[7] = fmaf(emb, g1.w, gp[7]);
    }

    #pragma unroll
    for (int off = 32; off > 0; off >>= 1) {
        #pragma unroll
        for (int e = 0; e < E_; ++e) gp[e] += __shfl_down(gp[e], off);
    }
    if (lane == 0) {
        #pragma unroll
        for (int e = 0; e < E_; ++e) gpart[w][e] = gp[e];
    }
    __syncthreads();
    if (tid < E_)
        logits[b * E_ + tid] =
            gpart[0][tid] + gpart[1][tid] + gpart[2][tid] + gpart[3][tid];
}

// ---------------- 2. top-2 gating ----------------
__global__ __launch_bounds__(256) void gate_top2_kernel(
    const float* __restrict__ logits, const float* __restrict__ gate_b,
    int* __restrict__ topi, float* __restrict__ topg, int* __restrict__ counts)
{
    int b = blockIdx.x * 256 + threadIdx.x;
    int lane = threadIdx.x & 63;
    float l[E_];
    #pragma unroll
    for (int e = 0; e < E_; ++e) l[e] = logits[b * E_ + e] + gate_b[e];
    int e1 = 0; float v1 = l[0];
    #pragma unroll
    for (int e = 1; e < E_; ++e) if (l[e] > v1) { v1 = l[e]; e1 = e; }
    int e2 = -1; float v2 = -1e30f;
    #pragma unroll
    for (int e = 0; e < E_; ++e) if (e != e1 && l[e] > v2) { v2 = l[e]; e2 = e; }
    float ex = expf(v2 - v1);
    float g1 = 1.0f / (1.0f + ex);
    float g2 = ex / (1.0f + ex);
    topi[b * 2] = e1; topi[b * 2 + 1] = e2;
    topg[b * 2] = g1; topg[b * 2 + 1] = g2;
    #pragma unroll
    for (int e = 0; e < E_; ++e) {
        unsigned long long m1 = __ballot(e1 == e);
        unsigned long long m2 = __ballot(e2 == e);
        if (lane == 0) {
            int c = __popcll(m1) + __popcll(m2);
            if (c) atomicAdd(&counts[e], c);
        }
    }
}

// ---------------- 3. scan + dense tile tables ----------------
// tiles1: fc1 (BM=128), tiles2: fc2 (BM=64); entry = (e<<16)|tr
__global__ void scan_kernel(const int* __restrict__ counts, int* __restrict__ offsets,
                            int* __restrict__ tiles1, int* __restrict__ tiles2,
                            int* __restrict__ ntiles) {
    if (threadIdx.x == 0) {
        int s = 0, n1 = 0, n2 = 0;
        for (int e = 0; e < E_; ++e) {
            offsets[e] = s;
            int c = counts[e];
            for (int tr = 0; tr * 128 < c; ++tr) tiles1[n1++] = (e << 16) | tr;
            for (int tr = 0; tr * 64 < c; ++tr) tiles2[n2++] = (e << 16) | tr;
            s += c;
        }
        offsets[E_] = s;
        ntiles[0] = n1;
        ntiles[1] = n2;
    }
}

// ---------------- 4. scatter samples into per-expert slot lists ----------------
__global__ __launch_bounds__(256) void scatter_kernel(
    const int* __restrict__ topi, const float* __restrict__ topg,
    const int* __restrict__ offsets, int* __restrict__ cursors,
    int* __restrict__ rows, float* __restrict__ gatev)
{
    int b = blockIdx.x * 256 + threadIdx.x;
    int lane = threadIdx.x & 63;
    #pragma unroll
    for (int j = 0; j < 2; ++j) {
        int e = topi[b * 2 + j];
        float g = topg[b * 2 + j];
        #pragma unroll
        for (int ex = 0; ex < E_; ++ex) {
            unsigned long long m = __ballot(e == ex);
            if (e == ex) {
                int leader = __builtin_ctzll(m);
                int base = 0;
                if (lane == leader) base = atomicAdd(&cursors[ex], __popcll(m));
                base = __shfl(base, leader);
                int pos = base + __popcll(m & ((1ull << lane) - 1ull));
                int slot = offsets[ex] + pos;
                rows[slot] = b;
                gatev[slot] = g;
            }
        }
    }
}

// ---------------- 5. transpose+convert: (CH,R,C) f32 -> (CH,C,R) bf16 ----------------
__global__ __launch_bounds__(256) void transp_bf16_kernel(
    const float* __restrict__ in, unsigned short* __restrict__ out, int R, int C)
{
    __shared__ float tile[64][65];
    int ch = blockIdx.z;
    const float* src = in + (size_t)ch * R * C;
    unsigned short* dst = out + (size_t)ch * R * C;
    int c0 = blockIdx.x * 64, r0 = blockIdx.y * 64;
    int lane = threadIdx.x & 63, w = threadIdx.x >> 6;
    #pragma unroll
    for (int i = 0; i < 16; ++i) {
        int r = w * 16 + i;
        tile[r][lane] = src[(size_t)(r0 + r) * C + c0 + lane];
    }
    __syncthreads();
    #pragma unroll
    for (int i = 0; i < 16; ++i) {
        int c = w * 16 + i;
        dst[(size_t)(c0 + c) * R + r0 + lane] = f2bf(tile[lane][c]);
    }
}

// ---------------- 6. FC1: 128x64 tile, dense tile table, fused bias+relu+bf16 ------
// bid = tile*16 + cn; consecutive blocks share the A-tile.
__global__ __launch_bounds__(256) void fc1_kernel(
    const unsigned short* __restrict__ Abf,   // flat_bf (B,F)
    const unsigned short* __restrict__ Wbt,   // (E,H,F) bf16
    const float* __restrict__ bias,           // (E,H)
    const int* __restrict__ rows, const int* __restrict__ offsets,
    const int* __restrict__ tiles1, const int* __restrict__ ntiles,
    unsigned short* __restrict__ Hbf)         // (NSLOT,H) bf16
{
    int bid = blockIdx.x;
    int tile = bid >> 4, cn = bid & 15;
    if (tile >= ntiles[0]) return;
    int te = tiles1[tile];
    int e = te >> 16, tr = te & 0xffff;
    int m0 = offsets[e], mEnd = offsets[e + 1];
    int Me = mEnd - m0;

    __shared__ alignas(16) unsigned short As[128 * 64];   // 16 KB
    __shared__ alignas(16) unsigned short Bs[64 * 64];    //  8 KB

    int tid = threadIdx.x, lane = tid & 63, wv = tid >> 6;
    int lr = lane >> 3;       // row within 8-row staging group
    int pchunk = lane & 7;    // LDS chunk position
    int cg = pchunk ^ lr;     // XOR swizzle -> 2-way-only bank aliasing

    const unsigned short* aptr[4];
    const unsigned short* bptr[2];
    #pragma unroll
    for (int i = 0; i < 4; ++i) {
        int rowA = (wv * 4 + i) * 8 + lr;
        int slot = min(m0 + tr * 128 + rowA, mEnd - 1);
        aptr[i] = Abf + (size_t)rows[slot] * F_ + cg * 8;
    }
    #pragma unroll
    for (int i = 0; i < 2; ++i) {
        int rowB = cn * 64 + (wv * 2 + i) * 8 + lr;
        bptr[i] = Wbt + ((size_t)e * H_ + rowB) * (size_t)F_ + cg * 8;
    }

    f32x4 zero = {0.f, 0.f, 0.f, 0.f};
    f32x4 acc[4][2];
    #pragma unroll
    for (int i = 0; i < 4; ++i)
        #pragma unroll
        for (int j = 0; j < 2; ++j) acc[i][j] = zero;

    int wvM = wv >> 1, wvN = wv & 1;
    int m16 = lane & 15, q = lane >> 4;

    for (int k0 = 0; k0 < F_; k0 += 64) {
        __syncthreads();
        #pragma unroll
        for (int i = 0; i < 4; ++i)
            gload_lds16(aptr[i] + k0, &As[(wv * 4 + i) * 512]);
        #pragma unroll
        for (int i = 0; i < 2; ++i)
            gload_lds16(bptr[i] + k0, &Bs[(wv * 2 + i) * 512]);
        __syncthreads();
        #pragma unroll
        for (int ks = 0; ks < 2; ++ks) {
            bf16x8 af[4], bfg[2];
            #pragma unroll
            for (int mt = 0; mt < 4; ++mt) {
                int m = wvM * 64 + mt * 16 + m16;
                int pos = (ks * 4 + q) ^ (m & 7);
                af[mt] = *(const bf16x8*)&As[m * 64 + pos * 8];
            }
            #pragma unroll
            for (int nt = 0; nt < 2; ++nt) {
                int n = wvN * 32 + nt * 16 + m16;
                int pos = (ks * 4 + q) ^ (n & 7);
                bfg[nt] = *(const bf16x8*)&Bs[n * 64 + pos * 8];
            }
            #pragma unroll
            for (int mt = 0; mt < 4; ++mt)
                #pragma unroll
                for (int nt = 0; nt < 2; ++nt)
                    acc[mt][nt] = __builtin_amdgcn_mfma_f32_16x16x32_bf16(
                        af[mt], bfg[nt], acc[mt][nt], 0, 0, 0);
        }
    }

    #pragma unroll
    for (int nt = 0; nt < 2; ++nt) {
        int col = cn * 64 + wvN * 32 + nt * 16 + m16;
        float bv = bias[e * H_ + col];
        #pragma unroll
        for (int mt = 0; mt < 4; ++mt) {
            int rbase = tr * 128 + wvM * 64 + mt * 16 + q * 4;
            #pragma unroll
            for (int r = 0; r < 4; ++r) {
                int rr = rbase + r;
                if (rr < Me) {
                    float v = fmaxf(acc[mt][nt][r] + bv, 0.0f);
                    Hbf[(size_t)(m0 + rr) * H_ + col] = f2bf(v);
                }
            }
        }
    }
}

// ---------------- 7. FC2: 64x64 tile, dense table, gated atomic combine ----------------
__global__ __launch_bounds__(256) void fc2_kernel(
    const unsigned short* __restrict__ Hbf,   // (NSLOT,H) bf16
    const unsigned short* __restrict__ Wbt,   // (E,O,H) bf16
    const float* __restrict__ bias,           // (E,O)
    const int* __restrict__ rows, const float* __restrict__ gatev,
    const int* __restrict__ offsets, const int* __restrict__ tiles2,
    const int* __restrict__ ntiles, float* __restrict__ moe)  // (B,O) f32
{
    int bid = blockIdx.x;
    int tile = bid >> 3, cn = bid & 7;
    if (tile >= ntiles[1]) return;
    int te = tiles2[tile];
    int e = te >> 16, tr = te & 0xffff;
    int m0 = offsets[e], mEnd = offsets[e + 1];
    int Me = mEnd - m0;

    __shared__ alignas(16) unsigned short As[64 * 64];   // 8 KB
    __shared__ alignas(16) unsigned short Bs[64 * 64];   // 8 KB

    int tid = threadIdx.x, lane = tid & 63, wv = tid >> 6;
    int lr = lane >> 3;
    int pchunk = lane & 7;
    int cg = pchunk ^ lr;

    const unsigned short* aptr[2];
    const unsigned short* bptr[2];
    #pragma unroll
    for (int i = 0; i < 2; ++i) {
        int rowA = (wv * 2 + i) * 8 + lr;
        int slot = min(m0 + tr * 64 + rowA, mEnd - 1);
        aptr[i] = Hbf + (size_t)slot * H_ + cg * 8;
        int rowB = cn * 64 + (wv * 2 + i) * 8 + lr;
        bptr[i] = Wbt + ((size_t)e * O_ + rowB) * (size_t)H_ + cg * 8;
    }

    f32x4 zero = {0.f, 0.f, 0.f, 0.f};
    f32x4 acc[4];
    #pragma unroll
    for (int i = 0; i < 4; ++i) acc[i] = zero;

    int m16 = lane & 15, q = lane >> 4;

    for (int k0 = 0; k0 < H_; k0 += 64) {
        __syncthreads();
        #pragma unroll
        for (int i = 0; i < 2; ++i) {
            gload_lds16(aptr[i] + k0, &As[(wv * 2 + i) * 512]);
            gload_lds16(bptr[i] + k0, &Bs[(wv * 2 + i) * 512]);
        }
        __syncthreads();
        #pragma unroll
        for (int ks = 0; ks < 2; ++ks) {
            bf16x8 af[4], bfg;
            #pragma unroll
            for (int mt = 0; mt < 4; ++mt) {
                int m = mt * 16 + m16;
                int pos = (ks * 4 + q) ^ (m & 7);
                af[mt] = *(const bf16x8*)&As[m * 64 + pos * 8];
            }
            {
                int n = wv * 16 + m16;
                int pos = (ks * 4 + q) ^ (n & 7);
                bfg = *(const bf16x8*)&Bs[n * 64 + pos * 8];
            }
            #pragma unroll
            for (int mt = 0; mt < 4; ++mt)
                acc[mt] = __builtin_amdgcn_mfma_f32_16x16x32_bf16(
                    af[mt], bfg, acc[mt], 0, 0, 0);
        }
    }

    int col = cn * 64 + wv * 16 + m16;
    float bv = bias[e * O_ + col];
    #pragma unroll
    for (int mt = 0; mt < 4; ++mt) {
        int rbase = tr * 64 + mt * 16 + q * 4;
        #pragma unroll
        for (int r = 0; r < 4; ++r) {
            int rr = rbase + r;
            if (rr < Me) {
                int slot = m0 + rr;
                float g = gatev[slot];
                int b = rows[slot];
                atomicAdd(&moe[(size_t)b * O_ + col], g * (acc[mt][r] + bv));
            }
        }
    }
}

// ---------------- 8. tower hidden: th = relu(moe @ tw1 + tb1), fp32 ----------------
__global__ __launch_bounds__(256) void tower1_kernel(
    const float* __restrict__ moe, const float* __restrict__ tw1,
    const float* __restrict__ tb1, float* __restrict__ th)
{
    __shared__ float ms[16 * O_];   // 32 KB
    int b0 = blockIdx.x * 16;
    int tid = threadIdx.x;
    for (int idx = tid; idx < 16 * O_; idx += 256)
        ms[idx] = moe[(size_t)b0 * O_ + idx];
    __syncthreads();

    int s = tid;
    float acc0[16], acc1[16];
    float bv0 = tb1[s], bv1 = tb1[TH_ + s];
    #pragma unroll
    for (int i = 0; i < 16; ++i) { acc0[i] = bv0; acc1[i] = bv1; }

    for (int o = 0; o < O_; o += 4) {
        float w0[4], w1[4];
        #pragma unroll
        for (int u = 0; u < 4; ++u) {
            w0[u] = tw1[(size_t)(o + u) * TH_ + s];
            w1[u] = tw1[(size_t)(O_ + o + u) * TH_ + s];
        }
        #pragma unroll
        for (int smp = 0; smp < 16; ++smp) {
            float4 mv = *(const float4*)&ms[smp * O_ + o];
            acc0[smp] = fmaf(mv.x, w0[0], acc0[smp]);
            acc0[smp] = fmaf(mv.y, w0[1], acc0[smp]);
            acc0[smp] = fmaf(mv.z, w0[2], acc0[smp]);
            acc0[smp] = fmaf(mv.w, w0[3], acc0[smp]);
            acc1[smp] = fmaf(mv.x, w1[0], acc1[smp]);
            acc1[smp] = fmaf(mv.y, w1[1], acc1[smp]);
            acc1[smp] = fmaf(mv.z, w1[2], acc1[smp]);
            acc1[smp] = fmaf(mv.w, w1[3], acc1[smp]);
        }
    }
    #pragma unroll
    for (int smp = 0; smp < 16; ++smp) {
        int b = b0 + smp;
        th[((size_t)b * T_ + 0) * TH_ + s] = fmaxf(acc0[smp], 0.0f);
        th[((size_t)b * T_ + 1) * TH_ + s] = fmaxf(acc1[smp], 0.0f);
    }
}

// ---------------- 9. tower out ----------------
__global__ __launch_bounds__(256) void tower2_kernel(
    const float* __restrict__ th, const float* __restrict__ tw2,
    const float* __restrict__ tb2, float* __restrict__ out)
{
    int tid = threadIdx.x, lane = tid & 63, w = tid >> 6;
    int pair = blockIdx.x * 4 + w;     // b*T + t
    int t = pair & 1;
    const float* tp = th + (size_t)pair * TH_;
    float p = 0.0f;
    #pragma unroll
    for (int j = 0; j < TH_ / 64; ++j) {
        int s = lane + j * 64;
        p = fmaf(tp[s], tw2[t * TH_ + s], p);
    }
    #pragma unroll
    for (int off = 32; off > 0; off >>= 1) p += __shfl_down(p, off);
    if (lane == 0) out[pair] = p + tb2[t];
}

extern "C" void kernel_launch(void* const* d_in, const int* in_sizes, int n_in,
                              void* d_out, int out_size, void* d_ws, size_t ws_size,
                              hipStream_t stream)
{
    const float* x     = (const float*)d_in[0];
    const float* plw   = (const float*)d_in[1];
    const float* plb   = (const float*)d_in[2];
    const float* embW  = (const float*)d_in[3];
    const float* embB  = (const float*)d_in[4];
    const float* gateW = (const float*)d_in[5];
    const float* gateB = (const float*)d_in[6];
    const float* eW1   = (const float*)d_in[7];
    const float* eB1   = (const float*)d_in[8];
    const float* eW2   = (const float*)d_in[9];
    const float* eB2   = (const float*)d_in[10];
    const float* tw1   = (const float*)d_in[11];
    const float* tb1   = (const float*)d_in[12];
    const float* tw2   = (const float*)d_in[13];
    const float* tb2   = (const float*)d_in[14];
    float* out = (float*)d_out;

    char* w = (char*)d_ws;
    auto alloc = [&](size_t bytes) {
        char* p = w; w += (bytes + 255) & ~(size_t)255; return p;
    };
    unsigned short* flat_bf = (unsigned short*)alloc((size_t)B_ * F_ * 2);      // 33.6 MB
    unsigned short* W1bt    = (unsigned short*)alloc((size_t)E_ * H_ * F_ * 2); // 67.1 MB
    unsigned short* W2bt    = (unsigned short*)alloc((size_t)E_ * O_ * H_ * 2); //  8.4 MB
    unsigned short* Hbf     = (unsigned short*)alloc((size_t)NSLOT * H_ * 2);   // 16.8 MB
    float* Ppre    = (float*)alloc((size_t)N_ * K_ * D_ * 4);                   // 786 KB
    float* logits  = (float*)alloc((size_t)B_ * E_ * 4);
    float* moe     = (float*)alloc((size_t)B_ * O_ * 4);                        //  8.4 MB
    float* th      = (float*)alloc((size_t)B_ * T_ * TH_ * 4);                  //  8.4 MB
    int*   topi    = (int*)alloc((size_t)B_ * 2 * 4);
    float* topg    = (float*)alloc((size_t)B_ * 2 * 4);
    int*   rows    = (int*)alloc((size_t)NSLOT * 4);
    float* gatev   = (float*)alloc((size_t)NSLOT * 4);
    int*   counts  = (int*)alloc(E_ * 4);
    int*   offsets = (int*)alloc((E_ + 1) * 4);
    int*   cursors = (int*)alloc(E_ * 4);
    int*   tiles1  = (int*)alloc(MAXT1 * 4);
    int*   tiles2  = (int*)alloc(MAXT2 * 4);
    int*   ntiles  = (int*)alloc(2 * 4);

    hipMemsetAsync(moe, 0, (size_t)B_ * O_ * 4, stream);
    hipMemsetAsync(counts, 0, E_ * 4, stream);
    hipMemsetAsync(cursors, 0, E_ * 4, stream);

    prefix_kernel<<<N_, 64, 0, stream>>>(embW, embB, Ppre);
    ple_embed_kernel<<<B_, 256, 0, stream>>>(x, plw, plb, embW, Ppre, gateW,
                                             flat_bf, logits);
    transp_bf16_kernel<<<dim3(H_ / 64, F_ / 64, E_), 256, 0, stream>>>(eW1, W1bt, F_, H_);
    transp_bf16_kernel<<<dim3(O_ / 64, H_ / 64, E_), 256, 0, stream>>>(eW2, W2bt, H_, O_);
    gate_top2_kernel<<<B_ / 256, 256, 0, stream>>>(logits, gateB, topi, topg, counts);
    scan_kernel<<<1, 64, 0, stream>>>(counts, offsets, tiles1, tiles2, ntiles);
    scatter_kernel<<<B_ / 256, 256, 0, stream>>>(topi, topg, offsets, cursors, rows, gatev);
    fc1_kernel<<<MAXT1 * 16, 256, 0, stream>>>(flat_bf, W1bt, eB1, rows, offsets,
                                               tiles1, ntiles, Hbf);
    fc2_kernel<<<MAXT2 * 8, 256, 0, stream>>>(Hbf, W2bt, eB2, rows, gatev, offsets,
                                              tiles2, ntiles, moe);
    tower1_kernel<<<B_ / 16, 256, 0, stream>>>(moe, tw1, tb1, th);
    tower2_kernel<<<B_ * T_ / 4, 256, 0, stream>>>(th, tw2, tb2, out);
}

// Round 6
// 574.794 us; speedup vs baseline: 1.5020x; 1.0457x over previous
//
#include <hip/hip_runtime.h>
#include <cstdint>

#define B_ 4096
#define N_ 64
#define K_ 48
#define D_ 64
#define F_ 4096
#define E_ 8
#define H_ 1024
#define O_ 512
#define T_ 2
#define TH_ 256
#define NSLOT (B_ * 2)

#define MAXT1 72    // sum over e of ceil(Me/128) <= 64+7

typedef float f32x4 __attribute__((ext_vector_type(4)));
typedef __bf16 bf16x8 __attribute__((ext_vector_type(8)));

__device__ __forceinline__ unsigned short f2bf(float f) {
    union { float f; unsigned int u; } v; v.f = f;
    unsigned int u = v.u;
    u += 0x7FFFu + ((u >> 16) & 1u);   // RNE
    return (unsigned short)(u >> 16);
}

__device__ __forceinline__ void gload_lds16(const void* gptr, void* lptr) {
    auto* g = reinterpret_cast<const __attribute__((address_space(1))) unsigned int*>(
        reinterpret_cast<uintptr_t>(gptr));
    auto* l = reinterpret_cast<__attribute__((address_space(3))) unsigned int*>(
        reinterpret_cast<uintptr_t>(lptr));
    __builtin_amdgcn_global_load_lds(g, l, 16, 0, 0);
}

// ---------------- 0. prefix sums of embW over k, bias folded in ----------------
__global__ __launch_bounds__(64) void prefix_kernel(
    const float* __restrict__ embW, const float* __restrict__ embB,
    float* __restrict__ P)
{
    int n = blockIdx.x;
    int lane = threadIdx.x;
    float acc = embB[n * D_ + lane];
    const float* wsrc = embW + (size_t)n * K_ * D_ + lane;
    float* dst = P + (size_t)n * K_ * D_ + lane;
    #pragma unroll 8
    for (int k = 0; k < K_; ++k) {
        dst[k * D_] = acc;
        acc += wsrc[k * D_];
    }
}

// ---------------- 1. PLE + embedding + gate logits ----------------
__global__ __launch_bounds__(256) void ple_embed_kernel(
    const float* __restrict__ x, const float* __restrict__ plw,
    const float* __restrict__ plb, const float* __restrict__ embW,
    const float* __restrict__ P, const float* __restrict__ gateW,
    unsigned short* __restrict__ flat_bf, float* __restrict__ logits)
{
    __shared__ float gpart[4][E_];
    int b = blockIdx.x;
    int tid = threadIdx.x, lane = tid & 63, w = tid >> 6;

    float xl = x[b * N_ + lane];
    float gp[E_];
    #pragma unroll
    for (int e = 0; e < E_; ++e) gp[e] = 0.0f;

    #pragma unroll 4
    for (int i = 0; i < 16; ++i) {
        int n = w * 16 + i;
        float xn = __shfl(xl, n);
        const float* pw = plw + n * K_;
        const float* pb = plb + n * K_;
        float t = fmaf(pw[0], xn, pb[0]);          // = K*x
        int j = (int)t;
        j = max(0, min(K_ - 1, j));
        float f = fminf(fmaxf(fmaf(pw[j], xn, pb[j]), 0.0f), 1.0f);
        size_t base = ((size_t)n * K_ + j) * D_ + lane;
        float emb = fmaxf(fmaf(f, embW[base], P[base]), 0.0f);
        flat_bf[(size_t)b * F_ + n * D_ + lane] = f2bf(emb);

        const float4* gw4 = (const float4*)(gateW + (size_t)(n * D_ + lane) * E_);
        float4 g0 = gw4[0], g1 = gw4[1];
        gp[0] = fmaf(emb, g0.x, gp[0]);
        gp[1] = fmaf(emb, g0.y, gp[1]);
        gp[2] = fmaf(emb, g0.z, gp[2]);
        gp[3] = fmaf(emb, g0.w, gp[3]);
        gp[4] = fmaf(emb, g1.x, gp[4]);
        gp[5] = fmaf(emb, g1.y, gp[5]);
        gp[6] = fmaf(emb, g1.z, gp[6]);
        gp[7] = fmaf(emb, g1.w, gp[7]);
    }

    #pragma unroll
    for (int off = 32; off > 0; off >>= 1) {
        #pragma unroll
        for (int e = 0; e < E_; ++e) gp[e] += __shfl_down(gp[e], off);
    }
    if (lane == 0) {
        #pragma unroll
        for (int e = 0; e < E_; ++e) gpart[w][e] = gp[e];
    }
    __syncthreads();
    if (tid < E_)
        logits[b * E_ + tid] =
            gpart[0][tid] + gpart[1][tid] + gpart[2][tid] + gpart[3][tid];
}

// ---------------- 2. top-2 gating ----------------
__global__ __launch_bounds__(256) void gate_top2_kernel(
    const float* __restrict__ logits, const float* __restrict__ gate_b,
    int* __restrict__ topi, float* __restrict__ topg, int* __restrict__ counts)
{
    int b = blockIdx.x * 256 + threadIdx.x;
    int lane = threadIdx.x & 63;
    float l[E_];
    #pragma unroll
    for (int e = 0; e < E_; ++e) l[e] = logits[b * E_ + e] + gate_b[e];
    int e1 = 0; float v1 = l[0];
    #pragma unroll
    for (int e = 1; e < E_; ++e) if (l[e] > v1) { v1 = l[e]; e1 = e; }
    int e2 = -1; float v2 = -1e30f;
    #pragma unroll
    for (int e = 0; e < E_; ++e) if (e != e1 && l[e] > v2) { v2 = l[e]; e2 = e; }
    float ex = expf(v2 - v1);
    float g1 = 1.0f / (1.0f + ex);
    float g2 = ex / (1.0f + ex);
    topi[b * 2] = e1; topi[b * 2 + 1] = e2;
    topg[b * 2] = g1; topg[b * 2 + 1] = g2;
    #pragma unroll
    for (int e = 0; e < E_; ++e) {
        unsigned long long m1 = __ballot(e1 == e);
        unsigned long long m2 = __ballot(e2 == e);
        if (lane == 0) {
            int c = __popcll(m1) + __popcll(m2);
            if (c) atomicAdd(&counts[e], c);
        }
    }
}

// ---------------- 3. scan + dense tile table (BM=128, shared by fc1/fc2) --------
__global__ void scan_kernel(const int* __restrict__ counts, int* __restrict__ offsets,
                            int* __restrict__ tiles1, int* __restrict__ ntiles) {
    int e = threadIdx.x;
    if (e >= E_) return;
    int c[E_];
    #pragma unroll
    for (int i = 0; i < E_; ++i) c[i] = counts[i];
    int off = 0, tb = 0, tot = 0, ttot = 0;
    #pragma unroll
    for (int i = 0; i < E_; ++i) {
        int t = (c[i] + 127) >> 7;
        if (i < e) { off += c[i]; tb += t; }
        tot += c[i]; ttot += t;
    }
    offsets[e] = off;
    if (e == 0) { offsets[E_] = tot; ntiles[0] = ttot; }
    int nt = (c[e] + 127) >> 7;
    for (int tr = 0; tr < nt; ++tr) tiles1[tb + tr] = (e << 16) | tr;
}

// ---------------- 4. scatter samples into per-expert slot lists ----------------
__global__ __launch_bounds__(256) void scatter_kernel(
    const int* __restrict__ topi, const float* __restrict__ topg,
    const int* __restrict__ offsets, int* __restrict__ cursors,
    int* __restrict__ rows, float* __restrict__ gatev)
{
    int b = blockIdx.x * 256 + threadIdx.x;
    int lane = threadIdx.x & 63;
    #pragma unroll
    for (int j = 0; j < 2; ++j) {
        int e = topi[b * 2 + j];
        float g = topg[b * 2 + j];
        #pragma unroll
        for (int ex = 0; ex < E_; ++ex) {
            unsigned long long m = __ballot(e == ex);
            if (e == ex) {
                int leader = __builtin_ctzll(m);
                int base = 0;
                if (lane == leader) base = atomicAdd(&cursors[ex], __popcll(m));
                base = __shfl(base, leader);
                int pos = base + __popcll(m & ((1ull << lane) - 1ull));
                int slot = offsets[ex] + pos;
                rows[slot] = b;
                gatev[slot] = g;
            }
        }
    }
}

// ---------------- 5. transpose+convert: (CH,R,C) f32 -> (CH,C,R) bf16 ----------------
__global__ __launch_bounds__(256) void transp_bf16_kernel(
    const float* __restrict__ in, unsigned short* __restrict__ out, int R, int C)
{
    __shared__ float tile[64][65];
    int ch = blockIdx.z;
    const float* src = in + (size_t)ch * R * C;
    unsigned short* dst = out + (size_t)ch * R * C;
    int c0 = blockIdx.x * 64, r0 = blockIdx.y * 64;
    int lane = threadIdx.x & 63, w = threadIdx.x >> 6;
    #pragma unroll
    for (int i = 0; i < 16; ++i) {
        int r = w * 16 + i;
        tile[r][lane] = src[(size_t)(r0 + r) * C + c0 + lane];
    }
    __syncthreads();
    #pragma unroll
    for (int i = 0; i < 16; ++i) {
        int c = w * 16 + i;
        dst[(size_t)(c0 + c) * R + r0 + lane] = f2bf(tile[lane][c]);
    }
}

// ---------------- 6. FC1: 128x128 tile, dense table, fused bias+relu+bf16 ------
// bid = tile*8 + cn. 4x4 fragments/wave: 16 ds_read_b128 feed 32 MFMA (0.5 r/m).
__global__ __launch_bounds__(256) void fc1_kernel(
    const unsigned short* __restrict__ Abf,   // flat_bf (B,F)
    const unsigned short* __restrict__ Wbt,   // (E,H,F) bf16
    const float* __restrict__ bias,           // (E,H)
    const int* __restrict__ rows, const int* __restrict__ offsets,
    const int* __restrict__ tiles1, const int* __restrict__ ntiles,
    unsigned short* __restrict__ Hbf)         // (NSLOT,H) bf16
{
    int bid = blockIdx.x;
    int tile = bid >> 3, cn = bid & 7;
    if (tile >= ntiles[0]) return;
    int te = tiles1[tile];
    int e = te >> 16, tr = te & 0xffff;
    int m0 = offsets[e], mEnd = offsets[e + 1];
    int Me = mEnd - m0;

    __shared__ alignas(16) unsigned short As[128 * 64];   // 16 KB
    __shared__ alignas(16) unsigned short Bs[128 * 64];   // 16 KB

    int tid = threadIdx.x, lane = tid & 63, wv = tid >> 6;
    int lr = lane >> 3;       // row within 8-row staging group
    int pchunk = lane & 7;
    int cg = pchunk ^ lr;     // XOR swizzle -> 2-way-only bank aliasing

    const unsigned short* aptr[4];
    const unsigned short* bptr[4];
    #pragma unroll
    for (int i = 0; i < 4; ++i) {
        int reg = wv * 4 + i;
        int rowA = reg * 8 + lr;
        int slot = min(m0 + tr * 128 + rowA, mEnd - 1);
        aptr[i] = Abf + (size_t)rows[slot] * F_ + cg * 8;
        int rowB = cn * 128 + reg * 8 + lr;
        bptr[i] = Wbt + ((size_t)e * H_ + rowB) * (size_t)F_ + cg * 8;
    }

    f32x4 zero = {0.f, 0.f, 0.f, 0.f};
    f32x4 acc[4][4];
    #pragma unroll
    for (int i = 0; i < 4; ++i)
        #pragma unroll
        for (int j = 0; j < 4; ++j) acc[i][j] = zero;

    int wvM = wv >> 1, wvN = wv & 1;
    int m16 = lane & 15, q = lane >> 4;

    for (int k0 = 0; k0 < F_; k0 += 64) {
        __syncthreads();
        #pragma unroll
        for (int i = 0; i < 4; ++i) {
            int reg = wv * 4 + i;
            gload_lds16(aptr[i] + k0, &As[reg * 512]);
            gload_lds16(bptr[i] + k0, &Bs[reg * 512]);
        }
        __syncthreads();
        #pragma unroll
        for (int ks = 0; ks < 2; ++ks) {
            bf16x8 af[4], bfg[4];
            #pragma unroll
            for (int mt = 0; mt < 4; ++mt) {
                int m = wvM * 64 + mt * 16 + m16;
                int pos = (ks * 4 + q) ^ (m & 7);
                af[mt] = *(const bf16x8*)&As[m * 64 + pos * 8];
            }
            #pragma unroll
            for (int nt = 0; nt < 4; ++nt) {
                int n = wvN * 64 + nt * 16 + m16;
                int pos = (ks * 4 + q) ^ (n & 7);
                bfg[nt] = *(const bf16x8*)&Bs[n * 64 + pos * 8];
            }
            #pragma unroll
            for (int mt = 0; mt < 4; ++mt)
                #pragma unroll
                for (int nt = 0; nt < 4; ++nt)
                    acc[mt][nt] = __builtin_amdgcn_mfma_f32_16x16x32_bf16(
                        af[mt], bfg[nt], acc[mt][nt], 0, 0, 0);
        }
    }

    #pragma unroll
    for (int nt = 0; nt < 4; ++nt) {
        int col = cn * 128 + wvN * 64 + nt * 16 + m16;
        float bv = bias[e * H_ + col];
        #pragma unroll
        for (int mt = 0; mt < 4; ++mt) {
            int rbase = tr * 128 + wvM * 64 + mt * 16 + q * 4;
            #pragma unroll
            for (int r = 0; r < 4; ++r) {
                int rr = rbase + r;
                if (rr < Me) {
                    float v = fmaxf(acc[mt][nt][r] + bv, 0.0f);
                    Hbf[(size_t)(m0 + rr) * H_ + col] = f2bf(v);
                }
            }
        }
    }
}

// ---------------- 7. FC2: 128x64 tile, same table, gated atomic combine ----------------
__global__ __launch_bounds__(256) void fc2_kernel(
    const unsigned short* __restrict__ Hbf,   // (NSLOT,H) bf16
    const unsigned short* __restrict__ Wbt,   // (E,O,H) bf16
    const float* __restrict__ bias,           // (E,O)
    const int* __restrict__ rows, const float* __restrict__ gatev,
    const int* __restrict__ offsets, const int* __restrict__ tiles1,
    const int* __restrict__ ntiles, float* __restrict__ moe)  // (B,O) f32
{
    int bid = blockIdx.x;
    int tile = bid >> 3, cn = bid & 7;
    if (tile >= ntiles[0]) return;
    int te = tiles1[tile];
    int e = te >> 16, tr = te & 0xffff;
    int m0 = offsets[e], mEnd = offsets[e + 1];
    int Me = mEnd - m0;

    __shared__ alignas(16) unsigned short As[128 * 64];   // 16 KB
    __shared__ alignas(16) unsigned short Bs[64 * 64];    //  8 KB

    int tid = threadIdx.x, lane = tid & 63, wv = tid >> 6;
    int lr = lane >> 3;
    int pchunk = lane & 7;
    int cg = pchunk ^ lr;

    const unsigned short* aptr[4];
    const unsigned short* bptr[2];
    #pragma unroll
    for (int i = 0; i < 4; ++i) {
        int rowA = (wv * 4 + i) * 8 + lr;
        int slot = min(m0 + tr * 128 + rowA, mEnd - 1);
        aptr[i] = Hbf + (size_t)slot * H_ + cg * 8;
    }
    #pragma unroll
    for (int i = 0; i < 2; ++i) {
        int rowB = cn * 64 + (wv * 2 + i) * 8 + lr;
        bptr[i] = Wbt + ((size_t)e * O_ + rowB) * (size_t)H_ + cg * 8;
    }

    f32x4 zero = {0.f, 0.f, 0.f, 0.f};
    f32x4 acc[4][2];
    #pragma unroll
    for (int i = 0; i < 4; ++i)
        #pragma unroll
        for (int j = 0; j < 2; ++j) acc[i][j] = zero;

    int wvM = wv >> 1, wvN = wv & 1;
    int m16 = lane & 15, q = lane >> 4;

    for (int k0 = 0; k0 < H_; k0 += 64) {
        __syncthreads();
        #pragma unroll
        for (int i = 0; i < 4; ++i)
            gload_lds16(aptr[i] + k0, &As[(wv * 4 + i) * 512]);
        #pragma unroll
        for (int i = 0; i < 2; ++i)
            gload_lds16(bptr[i] + k0, &Bs[(wv * 2 + i) * 512]);
        __syncthreads();
        #pragma unroll
        for (int ks = 0; ks < 2; ++ks) {
            bf16x8 af[4], bfg[2];
            #pragma unroll
            for (int mt = 0; mt < 4; ++mt) {
                int m = wvM * 64 + mt * 16 + m16;
                int pos = (ks * 4 + q) ^ (m & 7);
                af[mt] = *(const bf16x8*)&As[m * 64 + pos * 8];
            }
            #pragma unroll
            for (int nt = 0; nt < 2; ++nt) {
                int n = wvN * 32 + nt * 16 + m16;
                int pos = (ks * 4 + q) ^ (n & 7);
                bfg[nt] = *(const bf16x8*)&Bs[n * 64 + pos * 8];
            }
            #pragma unroll
            for (int mt = 0; mt < 4; ++mt)
                #pragma unroll
                for (int nt = 0; nt < 2; ++nt)
                    acc[mt][nt] = __builtin_amdgcn_mfma_f32_16x16x32_bf16(
                        af[mt], bfg[nt], acc[mt][nt], 0, 0, 0);
        }
    }

    #pragma unroll
    for (int nt = 0; nt < 2; ++nt) {
        int col = cn * 64 + wvN * 32 + nt * 16 + m16;
        float bv = bias[e * O_ + col];
        #pragma unroll
        for (int mt = 0; mt < 4; ++mt) {
            int rbase = tr * 128 + wvM * 64 + mt * 16 + q * 4;
            #pragma unroll
            for (int r = 0; r < 4; ++r) {
                int rr = rbase + r;
                if (rr < Me) {
                    int slot = m0 + rr;
                    float g = gatev[slot];
                    int b = rows[slot];
                    atomicAdd(&moe[(size_t)b * O_ + col], g * (acc[mt][nt][r] + bv));
                }
            }
        }
    }
}

// ---------------- 8. fused towers: out[b][t] = relu(moe@tw1+tb1) . tw2 + tb2 -------
// 8 samples/block (512 blocks); s = tid; both tasks per thread; all fp32.
__global__ __launch_bounds__(256) void tower_kernel(
    const float* __restrict__ moe, const float* __restrict__ tw1,
    const float* __restrict__ tb1, const float* __restrict__ tw2,
    const float* __restrict__ tb2, float* __restrict__ out)
{
    __shared__ float ms[8 * O_];       // 16 KB
    __shared__ float red[16][4];
    int b0 = blockIdx.x * 8;
    int tid = threadIdx.x, lane = tid & 63, wv = tid >> 6;
    for (int idx = tid; idx < 8 * O_; idx += 256)
        ms[idx] = moe[(size_t)b0 * O_ + idx];
    __syncthreads();

    int s = tid;
    float a0[8], a1[8];
    float bv0 = tb1[s], bv1 = tb1[TH_ + s];
    #pragma unroll
    for (int i = 0; i < 8; ++i) { a0[i] = bv0; a1[i] = bv1; }

    for (int o = 0; o < O_; o += 4) {
        float w0[4], w1[4];
        #pragma unroll
        for (int u = 0; u < 4; ++u) {
            w0[u] = tw1[(size_t)(o + u) * TH_ + s];
            w1[u] = tw1[(size_t)(O_ + o + u) * TH_ + s];
        }
        #pragma unroll
        for (int i = 0; i < 8; ++i) {
            float4 mv = *(const float4*)&ms[i * O_ + o];   // wave-broadcast, free
            a0[i] = fmaf(mv.x, w0[0], a0[i]);
            a0[i] = fmaf(mv.y, w0[1], a0[i]);
            a0[i] = fmaf(mv.z, w0[2], a0[i]);
            a0[i] = fmaf(mv.w, w0[3], a0[i]);
            a1[i] = fmaf(mv.x, w1[0], a1[i]);
            a1[i] = fmaf(mv.y, w1[1], a1[i]);
            a1[i] = fmaf(mv.z, w1[2], a1[i]);
            a1[i] = fmaf(mv.w, w1[3], a1[i]);
        }
    }

    float w2a = tw2[s], w2b = tw2[TH_ + s];
    #pragma unroll
    for (int i = 0; i < 8; ++i) {
        float p0 = fmaxf(a0[i], 0.0f) * w2a;
        float p1 = fmaxf(a1[i], 0.0f) * w2b;
        #pragma unroll
        for (int off = 32; off > 0; off >>= 1) {
            p0 += __shfl_down(p0, off);
            p1 += __shfl_down(p1, off);
        }
        if (lane == 0) { red[i * 2 + 0][wv] = p0; red[i * 2 + 1][wv] = p1; }
    }
    __syncthreads();
    if (tid < 16) {
        int i = tid >> 1, t = tid & 1;
        float v = red[tid][0] + red[tid][1] + red[tid][2] + red[tid][3] + tb2[t];
        out[(size_t)(b0 + i) * T_ + t] = v;
    }
}

extern "C" void kernel_launch(void* const* d_in, const int* in_sizes, int n_in,
                              void* d_out, int out_size, void* d_ws, size_t ws_size,
                              hipStream_t stream)
{
    const float* x     = (const float*)d_in[0];
    const float* plw   = (const float*)d_in[1];
    const float* plb   = (const float*)d_in[2];
    const float* embW  = (const float*)d_in[3];
    const float* embB  = (const float*)d_in[4];
    const float* gateW = (const float*)d_in[5];
    const float* gateB = (const float*)d_in[6];
    const float* eW1   = (const float*)d_in[7];
    const float* eB1   = (const float*)d_in[8];
    const float* eW2   = (const float*)d_in[9];
    const float* eB2   = (const float*)d_in[10];
    const float* tw1   = (const float*)d_in[11];
    const float* tb1   = (const float*)d_in[12];
    const float* tw2   = (const float*)d_in[13];
    const float* tb2   = (const float*)d_in[14];
    float* out = (float*)d_out;

    char* w = (char*)d_ws;
    auto alloc = [&](size_t bytes) {
        char* p = w; w += (bytes + 255) & ~(size_t)255; return p;
    };
    unsigned short* flat_bf = (unsigned short*)alloc((size_t)B_ * F_ * 2);      // 33.6 MB
    unsigned short* W1bt    = (unsigned short*)alloc((size_t)E_ * H_ * F_ * 2); // 67.1 MB
    unsigned short* W2bt    = (unsigned short*)alloc((size_t)E_ * O_ * H_ * 2); //  8.4 MB
    unsigned short* Hbf     = (unsigned short*)alloc((size_t)NSLOT * H_ * 2);   // 16.8 MB
    float* Ppre    = (float*)alloc((size_t)N_ * K_ * D_ * 4);                   // 786 KB
    float* logits  = (float*)alloc((size_t)B_ * E_ * 4);
    float* moe     = (float*)alloc((size_t)B_ * O_ * 4);                        //  8.4 MB
    int*   topi    = (int*)alloc((size_t)B_ * 2 * 4);
    float* topg    = (float*)alloc((size_t)B_ * 2 * 4);
    int*   rows    = (int*)alloc((size_t)NSLOT * 4);
    float* gatev   = (float*)alloc((size_t)NSLOT * 4);
    int*   counts  = (int*)alloc(E_ * 4);
    int*   offsets = (int*)alloc((E_ + 1) * 4);
    int*   cursors = (int*)alloc(E_ * 4);
    int*   tiles1  = (int*)alloc(MAXT1 * 4);
    int*   ntiles  = (int*)alloc(2 * 4);

    hipMemsetAsync(moe, 0, (size_t)B_ * O_ * 4, stream);
    hipMemsetAsync(counts, 0, E_ * 4, stream);
    hipMemsetAsync(cursors, 0, E_ * 4, stream);

    prefix_kernel<<<N_, 64, 0, stream>>>(embW, embB, Ppre);
    ple_embed_kernel<<<B_, 256, 0, stream>>>(x, plw, plb, embW, Ppre, gateW,
                                             flat_bf, logits);
    transp_bf16_kernel<<<dim3(H_ / 64, F_ / 64, E_), 256, 0, stream>>>(eW1, W1bt, F_, H_);
    transp_bf16_kernel<<<dim3(O_ / 64, H_ / 64, E_), 256, 0, stream>>>(eW2, W2bt, H_, O_);
    gate_top2_kernel<<<B_ / 256, 256, 0, stream>>>(logits, gateB, topi, topg, counts);
    scan_kernel<<<1, 64, 0, stream>>>(counts, offsets, tiles1, ntiles);
    scatter_kernel<<<B_ / 256, 256, 0, stream>>>(topi, topg, offsets, cursors, rows, gatev);
    fc1_kernel<<<MAXT1 * 8, 256, 0, stream>>>(flat_bf, W1bt, eB1, rows, offsets,
                                              tiles1, ntiles, Hbf);
    fc2_kernel<<<MAXT1 * 8, 256, 0, stream>>>(Hbf, W2bt, eB2, rows, gatev, offsets,
                                              tiles1, ntiles, moe);
    tower_kernel<<<B_ / 8, 256, 0, stream>>>(moe, tw1, tb1, tw2, tb2, out);
}

// Round 7
// 558.186 us; speedup vs baseline: 1.5467x; 1.0298x over previous
//
#include <hip/hip_runtime.h>
#include <cstdint>

#define B_ 4096
#define N_ 64
#define K_ 48
#define D_ 64
#define F_ 4096
#define E_ 8
#define H_ 1024
#define O_ 512
#define T_ 2
#define TH_ 256
#define NSLOT (B_ * 2)

#define MAXT1 72    // sum over e of ceil(Me/128) <= 64+7

typedef float f32x4 __attribute__((ext_vector_type(4)));
typedef __bf16 bf16x8 __attribute__((ext_vector_type(8)));

__device__ __forceinline__ unsigned short f2bf(float f) {
    union { float f; unsigned int u; } v; v.f = f;
    unsigned int u = v.u;
    u += 0x7FFFu + ((u >> 16) & 1u);   // RNE
    return (unsigned short)(u >> 16);
}

__device__ __forceinline__ void gload_lds16(const void* gptr, void* lptr) {
    auto* g = reinterpret_cast<const __attribute__((address_space(1))) unsigned int*>(
        reinterpret_cast<uintptr_t>(gptr));
    auto* l = reinterpret_cast<__attribute__((address_space(3))) unsigned int*>(
        reinterpret_cast<uintptr_t>(lptr));
    __builtin_amdgcn_global_load_lds(g, l, 16, 0, 0);
}

// ---------------- 0. prefix sums of embW over k, bias folded in ----------------
__global__ __launch_bounds__(64) void prefix_kernel(
    const float* __restrict__ embW, const float* __restrict__ embB,
    float* __restrict__ P)
{
    int n = blockIdx.x;
    int lane = threadIdx.x;
    float acc = embB[n * D_ + lane];
    const float* wsrc = embW + (size_t)n * K_ * D_ + lane;
    float* dst = P + (size_t)n * K_ * D_ + lane;
    #pragma unroll 8
    for (int k = 0; k < K_; ++k) {
        dst[k * D_] = acc;
        acc += wsrc[k * D_];
    }
}

// ---------------- 1. PLE + embedding + gate logits ----------------
__global__ __launch_bounds__(256) void ple_embed_kernel(
    const float* __restrict__ x, const float* __restrict__ plw,
    const float* __restrict__ plb, const float* __restrict__ embW,
    const float* __restrict__ P, const float* __restrict__ gateW,
    unsigned short* __restrict__ flat_bf, float* __restrict__ logits)
{
    __shared__ float gpart[4][E_];
    int b = blockIdx.x;
    int tid = threadIdx.x, lane = tid & 63, w = tid >> 6;

    float xl = x[b * N_ + lane];
    float gp[E_];
    #pragma unroll
    for (int e = 0; e < E_; ++e) gp[e] = 0.0f;

    #pragma unroll 4
    for (int i = 0; i < 16; ++i) {
        int n = w * 16 + i;
        float xn = __shfl(xl, n);
        const float* pw = plw + n * K_;
        const float* pb = plb + n * K_;
        float t = fmaf(pw[0], xn, pb[0]);          // = K*x
        int j = (int)t;
        j = max(0, min(K_ - 1, j));
        float f = fminf(fmaxf(fmaf(pw[j], xn, pb[j]), 0.0f), 1.0f);
        size_t base = ((size_t)n * K_ + j) * D_ + lane;
        float emb = fmaxf(fmaf(f, embW[base], P[base]), 0.0f);
        flat_bf[(size_t)b * F_ + n * D_ + lane] = f2bf(emb);

        const float4* gw4 = (const float4*)(gateW + (size_t)(n * D_ + lane) * E_);
        float4 g0 = gw4[0], g1 = gw4[1];
        gp[0] = fmaf(emb, g0.x, gp[0]);
        gp[1] = fmaf(emb, g0.y, gp[1]);
        gp[2] = fmaf(emb, g0.z, gp[2]);
        gp[3] = fmaf(emb, g0.w, gp[3]);
        gp[4] = fmaf(emb, g1.x, gp[4]);
        gp[5] = fmaf(emb, g1.y, gp[5]);
        gp[6] = fmaf(emb, g1.z, gp[6]);
        gp[7] = fmaf(emb, g1.w, gp[7]);
    }

    #pragma unroll
    for (int off = 32; off > 0; off >>= 1) {
        #pragma unroll
        for (int e = 0; e < E_; ++e) gp[e] += __shfl_down(gp[e], off);
    }
    if (lane == 0) {
        #pragma unroll
        for (int e = 0; e < E_; ++e) gpart[w][e] = gp[e];
    }
    __syncthreads();
    if (tid < E_)
        logits[b * E_ + tid] =
            gpart[0][tid] + gpart[1][tid] + gpart[2][tid] + gpart[3][tid];
}

// ---------------- 2. top-2 gating ----------------
__global__ __launch_bounds__(256) void gate_top2_kernel(
    const float* __restrict__ logits, const float* __restrict__ gate_b,
    int* __restrict__ topi, float* __restrict__ topg, int* __restrict__ counts)
{
    int b = blockIdx.x * 256 + threadIdx.x;
    int lane = threadIdx.x & 63;
    float l[E_];
    #pragma unroll
    for (int e = 0; e < E_; ++e) l[e] = logits[b * E_ + e] + gate_b[e];
    int e1 = 0; float v1 = l[0];
    #pragma unroll
    for (int e = 1; e < E_; ++e) if (l[e] > v1) { v1 = l[e]; e1 = e; }
    int e2 = -1; float v2 = -1e30f;
    #pragma unroll
    for (int e = 0; e < E_; ++e) if (e != e1 && l[e] > v2) { v2 = l[e]; e2 = e; }
    float ex = expf(v2 - v1);
    float g1 = 1.0f / (1.0f + ex);
    float g2 = ex / (1.0f + ex);
    topi[b * 2] = e1; topi[b * 2 + 1] = e2;
    topg[b * 2] = g1; topg[b * 2 + 1] = g2;
    #pragma unroll
    for (int e = 0; e < E_; ++e) {
        unsigned long long m1 = __ballot(e1 == e);
        unsigned long long m2 = __ballot(e2 == e);
        if (lane == 0) {
            int c = __popcll(m1) + __popcll(m2);
            if (c) atomicAdd(&counts[e], c);
        }
    }
}

// ---------------- 3. scan + dense tile table (BM=128, shared by fc1/fc2) --------
__global__ void scan_kernel(const int* __restrict__ counts, int* __restrict__ offsets,
                            int* __restrict__ tiles1, int* __restrict__ ntiles) {
    int e = threadIdx.x;
    if (e >= E_) return;
    int c[E_];
    #pragma unroll
    for (int i = 0; i < E_; ++i) c[i] = counts[i];
    int off = 0, tb = 0, tot = 0, ttot = 0;
    #pragma unroll
    for (int i = 0; i < E_; ++i) {
        int t = (c[i] + 127) >> 7;
        if (i < e) { off += c[i]; tb += t; }
        tot += c[i]; ttot += t;
    }
    offsets[e] = off;
    if (e == 0) { offsets[E_] = tot; ntiles[0] = ttot; }
    int nt = (c[e] + 127) >> 7;
    for (int tr = 0; tr < nt; ++tr) tiles1[tb + tr] = (e << 16) | tr;
}

// ---------------- 4. scatter samples into per-expert slot lists ----------------
__global__ __launch_bounds__(256) void scatter_kernel(
    const int* __restrict__ topi, const float* __restrict__ topg,
    const int* __restrict__ offsets, int* __restrict__ cursors,
    int* __restrict__ rows, float* __restrict__ gatev)
{
    int b = blockIdx.x * 256 + threadIdx.x;
    int lane = threadIdx.x & 63;
    #pragma unroll
    for (int j = 0; j < 2; ++j) {
        int e = topi[b * 2 + j];
        float g = topg[b * 2 + j];
        #pragma unroll
        for (int ex = 0; ex < E_; ++ex) {
            unsigned long long m = __ballot(e == ex);
            if (e == ex) {
                int leader = __builtin_ctzll(m);
                int base = 0;
                if (lane == leader) base = atomicAdd(&cursors[ex], __popcll(m));
                base = __shfl(base, leader);
                int pos = base + __popcll(m & ((1ull << lane) - 1ull));
                int slot = offsets[ex] + pos;
                rows[slot] = b;
                gatev[slot] = g;
            }
        }
    }
}

// ---------------- 5. weights -> MFMA-fragment order, f32 -> bf16 ----------------
// in: (E, R, C) f32 (R = K dim, C = output-col dim)
// out: [e][n0 = C/16][k0 = R/32][lane][8] bf16; a wave's B-fragment load is
// one coalesced 1 KB global_load_dwordx4 (lane-contiguous 16B each).
// Fragment element j of lane: (k = k0*32 + (lane>>4)*8 + j, n = n0*16 + (lane&15)).
__global__ __launch_bounds__(256) void wfrag_kernel(
    const float* __restrict__ in, unsigned short* __restrict__ out, int R, int C)
{
    __shared__ float tile[64][65];
    int e = blockIdx.z;
    int rb = blockIdx.x, cb = blockIdx.y;
    const float* src = in + (size_t)e * R * C + (size_t)(rb * 64) * C + cb * 64;
    int lane = threadIdx.x & 63, w = threadIdx.x >> 6;
    #pragma unroll
    for (int i = 0; i < 16; ++i) {
        int r = w * 16 + i;
        tile[r][lane] = src[(size_t)r * C + lane];
    }
    __syncthreads();
    int NB = C >> 4, KB = R >> 5;
    #pragma unroll
    for (int it = 0; it < 2; ++it) {
        int t = threadIdx.x + it * 256;
        int n0r = t >> 7, k0r = (t >> 6) & 1, ln = t & 63;
        int q = ln >> 4, nl = ln & 15;
        unsigned short v[8];
        #pragma unroll
        for (int j = 0; j < 8; ++j)
            v[j] = f2bf(tile[k0r * 32 + q * 8 + j][n0r * 16 + nl]);
        size_t didx = (((size_t)e * NB + cb * 4 + n0r) * KB + rb * 2 + k0r) * 512
                      + (size_t)ln * 8;
        uint4 pk;
        pk.x = v[0] | ((unsigned)v[1] << 16);
        pk.y = v[2] | ((unsigned)v[3] << 16);
        pk.z = v[4] | ((unsigned)v[5] << 16);
        pk.w = v[6] | ((unsigned)v[7] << 16);
        *(uint4*)&out[didx] = pk;
    }
}

// ---------------- 6. FC1: 128x64 tile, A via LDS, B direct-from-global frags ----
// bid = tile*16 + cn. As-only LDS (16 KB). B frags: coalesced 1KB global loads.
__global__ __launch_bounds__(256) void fc1_kernel(
    const unsigned short* __restrict__ Abf,   // flat_bf (B,F)
    const unsigned short* __restrict__ Wf,    // frag layout (E, H/16, F/32, 64, 8)
    const float* __restrict__ bias,           // (E,H)
    const int* __restrict__ rows, const int* __restrict__ offsets,
    const int* __restrict__ tiles1, const int* __restrict__ ntiles,
    unsigned short* __restrict__ Hbf)         // (NSLOT,H) bf16
{
    int bid = blockIdx.x;
    int tile = bid >> 4, cn = bid & 15;
    if (tile >= ntiles[0]) return;
    int te = tiles1[tile];
    int e = te >> 16, tr = te & 0xffff;
    int m0 = offsets[e], mEnd = offsets[e + 1];
    int Me = mEnd - m0;

    __shared__ alignas(16) unsigned short As[128 * 64];   // 16 KB

    int tid = threadIdx.x, lane = tid & 63, wv = tid >> 6;
    int lr = lane >> 3;
    int cg = (lane & 7) ^ lr;     // XOR swizzle -> 2-way-only bank aliasing

    const unsigned short* aptr[4];
    #pragma unroll
    for (int i = 0; i < 4; ++i) {
        int rowA = (wv * 4 + i) * 8 + lr;
        int slot = min(m0 + tr * 128 + rowA, mEnd - 1);
        aptr[i] = Abf + (size_t)rows[slot] * F_ + cg * 8;
    }

    int wvM = wv >> 1, wvN = wv & 1;
    int m16 = lane & 15, q = lane >> 4;

    const unsigned short* bbase[2];
    #pragma unroll
    for (int nt = 0; nt < 2; ++nt) {
        int n0 = cn * 4 + wvN * 2 + nt;
        bbase[nt] = Wf + (((size_t)e * (H_ / 16) + n0) * (F_ / 32)) * 512
                    + (size_t)lane * 8;
    }

    f32x4 zero = {0.f, 0.f, 0.f, 0.f};
    f32x4 acc[4][2];
    #pragma unroll
    for (int i = 0; i < 4; ++i)
        #pragma unroll
        for (int j = 0; j < 2; ++j) acc[i][j] = zero;

    for (int k0 = 0; k0 < F_; k0 += 64) {
        __syncthreads();
        #pragma unroll
        for (int i = 0; i < 4; ++i)
            gload_lds16(aptr[i] + k0, &As[(wv * 4 + i) * 512]);
        bf16x8 bfr[2][2];
        #pragma unroll
        for (int nt = 0; nt < 2; ++nt)
            #pragma unroll
            for (int ks = 0; ks < 2; ++ks)
                bfr[nt][ks] = *(const bf16x8*)(bbase[nt] + (size_t)k0 * 16 + ks * 512);
        __syncthreads();
        #pragma unroll
        for (int ks = 0; ks < 2; ++ks) {
            bf16x8 af[4];
            #pragma unroll
            for (int mt = 0; mt < 4; ++mt) {
                int m = wvM * 64 + mt * 16 + m16;
                int pos = (ks * 4 + q) ^ (m & 7);
                af[mt] = *(const bf16x8*)&As[m * 64 + pos * 8];
            }
            #pragma unroll
            for (int mt = 0; mt < 4; ++mt)
                #pragma unroll
                for (int nt = 0; nt < 2; ++nt)
                    acc[mt][nt] = __builtin_amdgcn_mfma_f32_16x16x32_bf16(
                        af[mt], bfr[nt][ks], acc[mt][nt], 0, 0, 0);
        }
    }

    #pragma unroll
    for (int nt = 0; nt < 2; ++nt) {
        int col = cn * 64 + wvN * 32 + nt * 16 + m16;
        float bv = bias[e * H_ + col];
        #pragma unroll
        for (int mt = 0; mt < 4; ++mt) {
            int rbase = tr * 128 + wvM * 64 + mt * 16 + q * 4;
            #pragma unroll
            for (int r = 0; r < 4; ++r) {
                int rr = rbase + r;
                if (rr < Me) {
                    float v = fmaxf(acc[mt][nt][r] + bv, 0.0f);
                    Hbf[(size_t)(m0 + rr) * H_ + col] = f2bf(v);
                }
            }
        }
    }
}

// ---------------- 7. FC2: 128x64 tile, B direct, gated atomic combine ----------------
__global__ __launch_bounds__(256) void fc2_kernel(
    const unsigned short* __restrict__ Hbf,   // (NSLOT,H) bf16
    const unsigned short* __restrict__ Wf,    // frag layout (E, O/16, H/32, 64, 8)
    const float* __restrict__ bias,           // (E,O)
    const int* __restrict__ rows, const float* __restrict__ gatev,
    const int* __restrict__ offsets, const int* __restrict__ tiles1,
    const int* __restrict__ ntiles, float* __restrict__ moe)  // (B,O) f32
{
    int bid = blockIdx.x;
    int tile = bid >> 3, cn = bid & 7;
    if (tile >= ntiles[0]) return;
    int te = tiles1[tile];
    int e = te >> 16, tr = te & 0xffff;
    int m0 = offsets[e], mEnd = offsets[e + 1];
    int Me = mEnd - m0;

    __shared__ alignas(16) unsigned short As[128 * 64];   // 16 KB

    int tid = threadIdx.x, lane = tid & 63, wv = tid >> 6;
    int lr = lane >> 3;
    int cg = (lane & 7) ^ lr;

    const unsigned short* aptr[4];
    #pragma unroll
    for (int i = 0; i < 4; ++i) {
        int rowA = (wv * 4 + i) * 8 + lr;
        int slot = min(m0 + tr * 128 + rowA, mEnd - 1);
        aptr[i] = Hbf + (size_t)slot * H_ + cg * 8;
    }

    int wvM = wv >> 1, wvN = wv & 1;
    int m16 = lane & 15, q = lane >> 4;

    const unsigned short* bbase[2];
    #pragma unroll
    for (int nt = 0; nt < 2; ++nt) {
        int n0 = cn * 4 + wvN * 2 + nt;
        bbase[nt] = Wf + (((size_t)e * (O_ / 16) + n0) * (H_ / 32)) * 512
                    + (size_t)lane * 8;
    }

    f32x4 zero = {0.f, 0.f, 0.f, 0.f};
    f32x4 acc[4][2];
    #pragma unroll
    for (int i = 0; i < 4; ++i)
        #pragma unroll
        for (int j = 0; j < 2; ++j) acc[i][j] = zero;

    for (int k0 = 0; k0 < H_; k0 += 64) {
        __syncthreads();
        #pragma unroll
        for (int i = 0; i < 4; ++i)
            gload_lds16(aptr[i] + k0, &As[(wv * 4 + i) * 512]);
        bf16x8 bfr[2][2];
        #pragma unroll
        for (int nt = 0; nt < 2; ++nt)
            #pragma unroll
            for (int ks = 0; ks < 2; ++ks)
                bfr[nt][ks] = *(const bf16x8*)(bbase[nt] + (size_t)k0 * 16 + ks * 512);
        __syncthreads();
        #pragma unroll
        for (int ks = 0; ks < 2; ++ks) {
            bf16x8 af[4];
            #pragma unroll
            for (int mt = 0; mt < 4; ++mt) {
                int m = wvM * 64 + mt * 16 + m16;
                int pos = (ks * 4 + q) ^ (m & 7);
                af[mt] = *(const bf16x8*)&As[m * 64 + pos * 8];
            }
            #pragma unroll
            for (int mt = 0; mt < 4; ++mt)
                #pragma unroll
                for (int nt = 0; nt < 2; ++nt)
                    acc[mt][nt] = __builtin_amdgcn_mfma_f32_16x16x32_bf16(
                        af[mt], bfr[nt][ks], acc[mt][nt], 0, 0, 0);
        }
    }

    #pragma unroll
    for (int nt = 0; nt < 2; ++nt) {
        int col = cn * 64 + wvN * 32 + nt * 16 + m16;
        float bv = bias[e * O_ + col];
        #pragma unroll
        for (int mt = 0; mt < 4; ++mt) {
            int rbase = tr * 128 + wvM * 64 + mt * 16 + q * 4;
            #pragma unroll
            for (int r = 0; r < 4; ++r) {
                int rr = rbase + r;
                if (rr < Me) {
                    int slot = m0 + rr;
                    float g = gatev[slot];
                    int b = rows[slot];
                    atomicAdd(&moe[(size_t)b * O_ + col], g * (acc[mt][nt][r] + bv));
                }
            }
        }
    }
}

// ---------------- 8. fused towers ----------------
__global__ __launch_bounds__(256) void tower_kernel(
    const float* __restrict__ moe, const float* __restrict__ tw1,
    const float* __restrict__ tb1, const float* __restrict__ tw2,
    const float* __restrict__ tb2, float* __restrict__ out)
{
    __shared__ float ms[8 * O_];       // 16 KB
    __shared__ float red[16][4];
    int b0 = blockIdx.x * 8;
    int tid = threadIdx.x, lane = tid & 63, wv = tid >> 6;
    for (int idx = tid; idx < 8 * O_; idx += 256)
        ms[idx] = moe[(size_t)b0 * O_ + idx];
    __syncthreads();

    int s = tid;
    float a0[8], a1[8];
    float bv0 = tb1[s], bv1 = tb1[TH_ + s];
    #pragma unroll
    for (int i = 0; i < 8; ++i) { a0[i] = bv0; a1[i] = bv1; }

    for (int o = 0; o < O_; o += 4) {
        float w0[4], w1[4];
        #pragma unroll
        for (int u = 0; u < 4; ++u) {
            w0[u] = tw1[(size_t)(o + u) * TH_ + s];
            w1[u] = tw1[(size_t)(O_ + o + u) * TH_ + s];
        }
        #pragma unroll
        for (int i = 0; i < 8; ++i) {
            float4 mv = *(const float4*)&ms[i * O_ + o];
            a0[i] = fmaf(mv.x, w0[0], a0[i]);
            a0[i] = fmaf(mv.y, w0[1], a0[i]);
            a0[i] = fmaf(mv.z, w0[2], a0[i]);
            a0[i] = fmaf(mv.w, w0[3], a0[i]);
            a1[i] = fmaf(mv.x, w1[0], a1[i]);
            a1[i] = fmaf(mv.y, w1[1], a1[i]);
            a1[i] = fmaf(mv.z, w1[2], a1[i]);
            a1[i] = fmaf(mv.w, w1[3], a1[i]);
        }
    }

    float w2a = tw2[s], w2b = tw2[TH_ + s];
    #pragma unroll
    for (int i = 0; i < 8; ++i) {
        float p0 = fmaxf(a0[i], 0.0f) * w2a;
        float p1 = fmaxf(a1[i], 0.0f) * w2b;
        #pragma unroll
        for (int off = 32; off > 0; off >>= 1) {
            p0 += __shfl_down(p0, off);
            p1 += __shfl_down(p1, off);
        }
        if (lane == 0) { red[i * 2 + 0][wv] = p0; red[i * 2 + 1][wv] = p1; }
    }
    __syncthreads();
    if (tid < 16) {
        int i = tid >> 1, t = tid & 1;
        float v = red[tid][0] + red[tid][1] + red[tid][2] + red[tid][3] + tb2[t];
        out[(size_t)(b0 + i) * T_ + t] = v;
    }
}

extern "C" void kernel_launch(void* const* d_in, const int* in_sizes, int n_in,
                              void* d_out, int out_size, void* d_ws, size_t ws_size,
                              hipStream_t stream)
{
    const float* x     = (const float*)d_in[0];
    const float* plw   = (const float*)d_in[1];
    const float* plb   = (const float*)d_in[2];
    const float* embW  = (const float*)d_in[3];
    const float* embB  = (const float*)d_in[4];
    const float* gateW = (const float*)d_in[5];
    const float* gateB = (const float*)d_in[6];
    const float* eW1   = (const float*)d_in[7];
    const float* eB1   = (const float*)d_in[8];
    const float* eW2   = (const float*)d_in[9];
    const float* eB2   = (const float*)d_in[10];
    const float* tw1   = (const float*)d_in[11];
    const float* tb1   = (const float*)d_in[12];
    const float* tw2   = (const float*)d_in[13];
    const float* tb2   = (const float*)d_in[14];
    float* out = (float*)d_out;

    char* w = (char*)d_ws;
    auto alloc = [&](size_t bytes) {
        char* p = w; w += (bytes + 255) & ~(size_t)255; return p;
    };
    unsigned short* flat_bf = (unsigned short*)alloc((size_t)B_ * F_ * 2);      // 33.6 MB
    unsigned short* W1f     = (unsigned short*)alloc((size_t)E_ * H_ * F_ * 2); // 67.1 MB
    unsigned short* W2f     = (unsigned short*)alloc((size_t)E_ * O_ * H_ * 2); //  8.4 MB
    unsigned short* Hbf     = (unsigned short*)alloc((size_t)NSLOT * H_ * 2);   // 16.8 MB
    float* Ppre    = (float*)alloc((size_t)N_ * K_ * D_ * 4);                   // 786 KB
    float* logits  = (float*)alloc((size_t)B_ * E_ * 4);
    float* moe     = (float*)alloc((size_t)B_ * O_ * 4);                        //  8.4 MB
    int*   topi    = (int*)alloc((size_t)B_ * 2 * 4);
    float* topg    = (float*)alloc((size_t)B_ * 2 * 4);
    int*   rows    = (int*)alloc((size_t)NSLOT * 4);
    float* gatev   = (float*)alloc((size_t)NSLOT * 4);
    int*   counts  = (int*)alloc(E_ * 4);
    int*   offsets = (int*)alloc((E_ + 1) * 4);
    int*   cursors = (int*)alloc(E_ * 4);
    int*   tiles1  = (int*)alloc(MAXT1 * 4);
    int*   ntiles  = (int*)alloc(2 * 4);

    hipMemsetAsync(moe, 0, (size_t)B_ * O_ * 4, stream);
    hipMemsetAsync(counts, 0, E_ * 4, stream);
    hipMemsetAsync(cursors, 0, E_ * 4, stream);

    prefix_kernel<<<N_, 64, 0, stream>>>(embW, embB, Ppre);
    ple_embed_kernel<<<B_, 256, 0, stream>>>(x, plw, plb, embW, Ppre, gateW,
                                             flat_bf, logits);
    wfrag_kernel<<<dim3(F_ / 64, H_ / 64, E_), 256, 0, stream>>>(eW1, W1f, F_, H_);
    wfrag_kernel<<<dim3(H_ / 64, O_ / 64, E_), 256, 0, stream>>>(eW2, W2f, H_, O_);
    gate_top2_kernel<<<B_ / 256, 256, 0, stream>>>(logits, gateB, topi, topg, counts);
    scan_kernel<<<1, 64, 0, stream>>>(counts, offsets, tiles1, ntiles);
    scatter_kernel<<<B_ / 256, 256, 0, stream>>>(topi, topg, offsets, cursors, rows, gatev);
    fc1_kernel<<<MAXT1 * 16, 256, 0, stream>>>(flat_bf, W1f, eB1, rows, offsets,
                                               tiles1, ntiles, Hbf);
    fc2_kernel<<<MAXT1 * 8, 256, 0, stream>>>(Hbf, W2f, eB2, rows, gatev, offsets,
                                              tiles1, ntiles, moe);
    tower_kernel<<<B_ / 8, 256, 0, stream>>>(moe, tw1, tb1, tw2, tb2, out);
}